// Round 1
// 1200.172 us; speedup vs baseline: 1.0051x; 1.0051x over previous
//
#include <hip/hip_runtime.h>
#include <hip/hip_bf16.h>

// Problem constants (fixed by reference setup_inputs)
#define N_ATOMS   100000
#define N_BONDS   200000
#define MAX_NB    6
#define HIDDEN    300
#define ATOM_FDIM 133
#define BOND_FDIM 147
#define N_MOLS    5000
#define APM       20      // atoms per mol

#define MB_ROWS (N_BONDS + 1)   // 200001
#define MA_ROWS (N_ATOMS + 1)   // 100001

#define CHUNKS_B 1280     // 16B chunks per k-block image: 4*320*8 bf16 = 20480 B
#define EPS      308      // epilogue LDS row stride in floats (304 cols + pad)

typedef unsigned short bf16_t;
typedef __attribute__((ext_vector_type(8))) __bf16 bf16x8;   // MFMA A/B frag
typedef __attribute__((ext_vector_type(4))) float  float4v;  // MFMA C/D frag

__device__ __forceinline__ float bf2f(unsigned short u) {
    union { unsigned int i; float f; } x; x.i = ((unsigned int)u) << 16; return x.f;
}
__device__ __forceinline__ unsigned short f2bf(float f) {
    union { float f; unsigned int i; } x; x.f = f;
    unsigned int r = x.i + 0x7FFFu + ((x.i >> 16) & 1u);   // RNE (finite values)
    return (unsigned short)(r >> 16);
}

// Raw barrier: NO waitcnt. Safe because every wave's frag ds_reads were
// consumed by MFMAs (compiler lgkm-waits) before reaching this point.
#define BAR_RAW() do {                              \
    __builtin_amdgcn_sched_barrier(0);              \
    asm volatile("" ::: "memory");                  \
    __builtin_amdgcn_s_barrier();                   \
    __builtin_amdgcn_sched_barrier(0);              \
} while (0)

// Barrier after ds_writes: drain LDS queue only (lgkm), never vmcnt —
// the kb+1 global prefetches must stay in flight across this barrier.
#define BAR_LGKM() do {                             \
    __builtin_amdgcn_sched_barrier(0);              \
    asm volatile("s_waitcnt lgkmcnt(0)" ::: "memory"); \
    __builtin_amdgcn_s_barrier();                   \
    __builtin_amdgcn_sched_barrier(0);              \
} while (0)

// ===========================================================================
// Weight prep: W fp32 [K][300] row-major -> bf16 k-block images matching the
// Bs LDS layout exactly: chunk c (16 B) of block kb holds, for cq=c/320,
// col=c%320: W[kb*32+cq*8+j][col], j=0..7; zero-padded (k>=K or col>=300).
// ===========================================================================
__global__ __launch_bounds__(256) void prep_w(
    const float* __restrict__ W, bf16_t* __restrict__ dst, int K, int total_chunks)
{
    int idx = blockIdx.x * 256 + threadIdx.x;
    if (idx >= total_chunks) return;
    int kb  = idx / CHUNKS_B;
    int c   = idx - kb * CHUNKS_B;
    int cq  = c / 320;
    int col = c - cq * 320;
    unsigned short v[8];
    #pragma unroll
    for (int j = 0; j < 8; ++j) {
        int k = kb * 32 + cq * 8 + j;
        float f = (k < K && col < HIDDEN) ? W[(size_t)k * HIDDEN + col] : 0.f;
        v[j] = f2bf(f);
    }
    bf16_t* p = dst + (size_t)idx * 8;
    *(ushort4*)(p)     = make_ushort4(v[0], v[1], v[2], v[3]);
    *(ushort4*)(p + 4) = make_ushort4(v[4], v[5], v[6], v[7]);
}

// ===========================================================================
// Pipelined MFMA GEMM (r7 core + this round's changes):
//   - quad-major LDS: As[q][row][8], Bs[q][col][8]; single-buffered (28 KB)
//   - verified maps: A m=lane&15 k=q*8+j; B n=lane&15 k=q*8+j;
//     C/D col=lane&15 row=q*4+reg
//   - SW pipeline: A-gather and B-chunks for kb+1 are issued into REGISTERS
//     mid-iteration; raw s_barrier (no vmcnt drain) lets them stay in flight
//     across both barriers + the MFMA phase. Compiler inserts the vmcnt wait
//     at first use (the convert step of the next iteration).
//   - Epilogue: acc staged to LDS (fp32, stride-308 padded) 16 rows at a
//     time, then coalesced ushort4 writeback (fixes 2.3x write amplification
//     and the scattered addend reads).
// Block: 512 thr = 8 waves (2m x 4n); tile 128(m) x 320(n) — full N per
// block, per-row gathers exactly once.
// MODE 0: A = f_bonds fp32 [M,147];            Y = relu(A@W)
// MODE 1: A = amsg[b2a[r]] - cur[b2revb[r]];   Y = relu(addend + A@W)
//         (Y may alias addend: same-element read-before-write only)
// MODE 2: A = [f_atoms fp32 (133) | amsg bf16 (300)]; Y = relu(A@W + bias)
// ===========================================================================
template<int MODE>
__global__ __launch_bounds__(512, 3) void gemm_mfma(
    const float* __restrict__ Af,
    const bf16_t* __restrict__ Ab1, const bf16_t* __restrict__ Ab2,
    const int* __restrict__ b2a, const int* __restrict__ b2revb,
    const bf16_t* __restrict__ WB, const float* __restrict__ bias,
    const bf16_t* __restrict__ addend, bf16_t* __restrict__ Y,
    int M, int KB)
{
    const int S = HIDDEN;   // output row stride 300
    // 28672 B pool: main loop = As(8K) + Bs(20K); epilogue = [16][308] fp32
    __shared__ __align__(16) char lds_pool[28672];
    typedef bf16_t AsT[4][128][8];
    typedef bf16_t BsT[4][320][8];
    AsT& As = *reinterpret_cast<AsT*>(lds_pool);
    BsT& Bs = *reinterpret_cast<BsT*>(lds_pool + 8192);
    bf16_t* BsL = &Bs[0][0][0];
    float* epi = reinterpret_cast<float*>(lds_pool);

    const int tid  = threadIdx.x;
    const int lane = tid & 63;
    const int w    = tid >> 6;        // 0..7
    const int wm   = w >> 2;          // m-half (0/1): 64 rows
    const int wn   = w & 3;           // n-quarter (0..3): 80 cols
    const int lrow = lane & 15;
    const int q    = lane >> 4;       // quad 0..3
    const int bm   = blockIdx.x * 128;

    // A-staging role: thread -> (row 0..127, quad 0..3), 8 k-elems each
    const int sr   = tid >> 2;
    const int sq   = tid & 3;
    const int srow = bm + sr;
    int ra = 0, rrev = 0;
    if (MODE == 1 && srow < M) { ra = b2a[srow]; rrev = b2revb[srow]; }
    // row 0 of amsg/msg is all-zero, so OOB rows (ra=rrev=0) load zeros.
    const bf16_t* pa = (MODE == 1) ? Ab1 + (size_t)ra   * S : nullptr;
    const bf16_t* pc = (MODE == 1) ? Ab2 + (size_t)rrev * S : nullptr;

    // B-staging role: chunks tid, tid+512, (tid+1024 if tid<256)
    const int c_b0 = tid, c_b1 = tid + 512, c_b2 = tid + 1024;

    float4v acc[4][5];
    #pragma unroll
    for (int i = 0; i < 4; ++i)
        #pragma unroll
        for (int j = 0; j < 5; ++j) {
            float4v z = {0.f, 0.f, 0.f, 0.f};
            acc[i][j] = z;
        }

    // ---- prefetch registers (live across the MFMA phase) -----------------
    uint4 b0, b1, b2;                         // B: 40 B/thread (12 VGPR)
    float fa[8];                              // MODE0/2 fp32 part
    ushort4 ua0, ua1, uc0, uc1;               // MODE1 gathered bf16
    unsigned short um[8];                     // MODE2 bf16 part

    auto issueB = [&](int kb) {
        const bf16_t* wsrc = WB + (size_t)kb * (CHUNKS_B * 8);
        b0 = *(const uint4*)(wsrc + (size_t)c_b0 * 8);
        b1 = *(const uint4*)(wsrc + (size_t)c_b1 * 8);
        if (tid < 256) b2 = *(const uint4*)(wsrc + (size_t)c_b2 * 8);
    };
    auto issueA = [&](int kb) {
        const int kq = kb * 32 + sq * 8;
        if (MODE == 0) {
            #pragma unroll
            for (int j = 0; j < 8; ++j) {
                int k = kq + j;
                fa[j] = (srow < M && k < BOND_FDIM)
                        ? Af[(size_t)srow * BOND_FDIM + k] : 0.f;
            }
        } else if (MODE == 1) {
            ua0 = ua1 = uc0 = uc1 = make_ushort4(0, 0, 0, 0);
            if (kq + 4 <= S) { ua0 = *(const ushort4*)(pa + kq);
                               uc0 = *(const ushort4*)(pc + kq); }
            if (kq + 8 <= S) { ua1 = *(const ushort4*)(pa + kq + 4);
                               uc1 = *(const ushort4*)(pc + kq + 4); }
        } else {   // MODE 2
            #pragma unroll
            for (int j = 0; j < 8; ++j) {
                int k = kq + j;
                fa[j] = 0.f; um[j] = 0;
                if (srow < M) {
                    if (k < ATOM_FDIM)
                        fa[j] = Af[(size_t)srow * ATOM_FDIM + k];
                    else if (k < ATOM_FDIM + HIDDEN)
                        um[j] = Ab1[(size_t)srow * S + (k - ATOM_FDIM)];
                }
            }
        }
    };
    auto convertA = [&](int kb, ushort4& lo, ushort4& hi) {
        unsigned short av[8];
        if (MODE == 0) {
            #pragma unroll
            for (int j = 0; j < 8; ++j) av[j] = f2bf(fa[j]);
        } else if (MODE == 1) {
            av[0] = f2bf(bf2f(ua0.x) - bf2f(uc0.x));
            av[1] = f2bf(bf2f(ua0.y) - bf2f(uc0.y));
            av[2] = f2bf(bf2f(ua0.z) - bf2f(uc0.z));
            av[3] = f2bf(bf2f(ua0.w) - bf2f(uc0.w));
            av[4] = f2bf(bf2f(ua1.x) - bf2f(uc1.x));
            av[5] = f2bf(bf2f(ua1.y) - bf2f(uc1.y));
            av[6] = f2bf(bf2f(ua1.z) - bf2f(uc1.z));
            av[7] = f2bf(bf2f(ua1.w) - bf2f(uc1.w));
        } else {
            const int kq = kb * 32 + sq * 8;
            #pragma unroll
            for (int j = 0; j < 8; ++j) {
                int k = kq + j;
                av[j] = (k < ATOM_FDIM) ? f2bf(fa[j]) : um[j];
            }
        }
        lo = make_ushort4(av[0], av[1], av[2], av[3]);
        hi = make_ushort4(av[4], av[5], av[6], av[7]);
    };

    // ---- prologue: fetch k-block 0 ---------------------------------------
    issueB(0); issueA(0);

    for (int kb = 0; kb < KB; ++kb) {
        // convert A[kb] (compiler inserts vmcnt wait on the gather here)
        ushort4 alo, ahi;
        convertA(kb, alo, ahi);
        // issue next A gather ASAP: latency spans barriers + MFMA phase
        if (kb + 1 < KB) issueA(kb + 1);

        BAR_RAW();     // all waves done READING LDS from iteration kb-1

        *(ushort4*)&As[sq][sr][0] = alo;
        *(ushort4*)&As[sq][sr][4] = ahi;
        *(uint4*)(BsL + (size_t)c_b0 * 8) = b0;
        *(uint4*)(BsL + (size_t)c_b1 * 8) = b1;
        if (tid < 256) *(uint4*)(BsL + (size_t)c_b2 * 8) = b2;
        if (kb + 1 < KB) issueB(kb + 1);   // B regs freed by writes above

        BAR_LGKM();    // LDS writes visible; vmem prefetches stay in flight

        bf16x8 af[4];
        #pragma unroll
        for (int mt = 0; mt < 4; ++mt)
            af[mt] = *(const bf16x8*)&As[q][wm * 64 + mt * 16 + lrow][0];
        #pragma unroll
        for (int nt = 0; nt < 5; ++nt) {
            const int c0 = wn * 80 + nt * 16;
            if (c0 < HIDDEN) {   // skip the all-pad tile (cols 304..319)
                bf16x8 bfr = *(const bf16x8*)&Bs[q][c0 + lrow][0];
                #pragma unroll
                for (int mt = 0; mt < 4; ++mt)
                    acc[mt][nt] = __builtin_amdgcn_mfma_f32_16x16x32_bf16(
                        af[mt], bfr, acc[mt][nt], 0, 0, 0);
            }
        }
    }

    // ---- epilogue: LDS transpose -> coalesced ushort4 rows ---------------
    // Stage 16 output rows at a time as fp32 (full precision kept until the
    // single final rounding), then 512 threads write 600 B/row contiguous.
    __syncthreads();   // safe to overwrite As/Bs pool
    #pragma unroll
    for (int mt = 0; mt < 4; ++mt) {
        for (int wh = 0; wh < 2; ++wh) {
            if (wm == wh) {
                #pragma unroll
                for (int nt = 0; nt < 5; ++nt) {
                    const int c0 = wn * 80 + nt * 16;
                    if (c0 < HIDDEN) {
                        #pragma unroll
                        for (int r = 0; r < 4; ++r)
                            epi[(q * 4 + r) * EPS + c0 + lrow] = acc[mt][nt][r];
                    }
                }
            }
            __syncthreads();
            const int row0 = bm + wh * 64 + mt * 16;
            for (int s = tid; s < 16 * 75; s += 512) {
                int rr = s / 75;
                int c4 = s - rr * 75;
                int grow = row0 + rr;
                if (grow < M) {
                    float4 v = *(const float4*)&epi[rr * EPS + c4 * 4];
                    if (MODE == 1) {
                        ushort4 ad = *(const ushort4*)(addend + (size_t)grow * S + c4 * 4);
                        v.x += bf2f(ad.x); v.y += bf2f(ad.y);
                        v.z += bf2f(ad.z); v.w += bf2f(ad.w);
                    }
                    if (MODE == 2) {
                        float4 bv = *(const float4*)(bias + c4 * 4);
                        v.x += bv.x; v.y += bv.y; v.z += bv.z; v.w += bv.w;
                    }
                    ushort4 o;
                    o.x = f2bf(v.x > 0.f ? v.x : 0.f);
                    o.y = f2bf(v.y > 0.f ? v.y : 0.f);
                    o.z = f2bf(v.z > 0.f ? v.z : 0.f);
                    o.w = f2bf(v.w > 0.f ? v.w : 0.f);
                    *(ushort4*)(Y + (size_t)grow * S + c4 * 4) = o;
                }
            }
            __syncthreads();   // before next stage overwrites epi
        }
    }
}

// ===========================================================================
// r2/r5-proven: aggregate + mol mean
// ===========================================================================

// amsg[a][:] = sum_j msg[a2b[a][j]][:]   (bf16 in/out, fp32 accumulate)
__global__ __launch_bounds__(256) void aggregate_k(
    const bf16_t* __restrict__ msg, const int* __restrict__ a2b,
    bf16_t* __restrict__ amsg)
{
    int idx = blockIdx.x * blockDim.x + threadIdx.x;
    const int total = MA_ROWS * 75;
    if (idx >= total) return;
    int a  = idx / 75;
    int c4 = idx - a * 75;
    const int* nb = a2b + (size_t)a * MAX_NB;
    float4 s = make_float4(0.f, 0.f, 0.f, 0.f);
    #pragma unroll
    for (int j = 0; j < MAX_NB; ++j) {
        int b = nb[j];
        ushort4 u = *(const ushort4*)(msg + (size_t)b * HIDDEN + c4 * 4);
        s.x += bf2f(u.x); s.y += bf2f(u.y); s.z += bf2f(u.z); s.w += bf2f(u.w);
    }
    ushort4 o;
    o.x = f2bf(s.x); o.y = f2bf(s.y); o.z = f2bf(s.z); o.w = f2bf(s.w);
    *(ushort4*)(amsg + (size_t)a * HIDDEN + c4 * 4) = o;
}

// mol_vecs[m][:] = mean over 20 consecutive atom rows (offset by 1), fp32 out
__global__ __launch_bounds__(256) void mol_mean_k(
    const bf16_t* __restrict__ atom_h, float* __restrict__ out)
{
    int idx = blockIdx.x * blockDim.x + threadIdx.x;
    if (idx >= N_MOLS * 75) return;
    int m  = idx / 75;
    int c4 = idx - m * 75;
    const bf16_t* base = atom_h + (size_t)(1 + m * APM) * HIDDEN + c4 * 4;
    float4 s = make_float4(0.f, 0.f, 0.f, 0.f);
    #pragma unroll
    for (int i = 0; i < APM; ++i) {
        ushort4 u = *(const ushort4*)(base + (size_t)i * HIDDEN);
        s.x += bf2f(u.x); s.y += bf2f(u.y); s.z += bf2f(u.z); s.w += bf2f(u.w);
    }
    const float inv = 1.0f / (float)APM;
    s.x *= inv; s.y *= inv; s.z *= inv; s.w *= inv;
    *(float4*)(out + (size_t)m * HIDDEN + c4 * 4) = s;
}

// ---------------------------------------------------------------------------
extern "C" void kernel_launch(void* const* d_in, const int* in_sizes, int n_in,
                              void* d_out, int out_size, void* d_ws, size_t ws_size,
                              hipStream_t stream)
{
    const float* f_atoms = (const float*)d_in[0];
    const float* f_bonds = (const float*)d_in[1];
    const float* W_i     = (const float*)d_in[2];
    const float* W_h     = (const float*)d_in[3];
    const float* W_o     = (const float*)d_in[4];
    const float* b_o     = (const float*)d_in[5];
    const int*   a2b     = (const int*)d_in[6];
    const int*   b2a     = (const int*)d_in[7];
    const int*   b2revb  = (const int*)d_in[8];
    float* out = (float*)d_out;

    // Workspace: r2/r5/r6-proven layout (300,002,136 B — do NOT grow d_ws!)
    char* base = (char*)d_ws;
    const size_t SZ_BOND_B = (((size_t)MB_ROWS * HIDDEN * sizeof(bf16_t)) + 255) & ~(size_t)255;
    bf16_t* inp  = (bf16_t*)(base);
    bf16_t* msgA = (bf16_t*)(base + SZ_BOND_B);
    bf16_t* amsg = (bf16_t*)(base + 2 * SZ_BOND_B);

    // Pre-blocked bf16 weights live in d_out scratch (6 MB; 593,920 B used).
    // Safe: fully consumed before mol_mean_k overwrites every output element.
    char* scratch = (char*)d_out;
    bf16_t* Wib = (bf16_t*)(scratch);                 //  5 kb * 20480 B = 102,400
    bf16_t* Whb = (bf16_t*)(scratch + 102400);        // 10 kb           = 204,800
    bf16_t* Wob = (bf16_t*)(scratch + 307200);        // 14 kb           = 286,720

    dim3 blk512(512), blk256(256);
    const int gb = (MB_ROWS + 127) / 128;   // 1563
    const int ga = (MA_ROWS + 127) / 128;   // 782
    int agg_blocks  = (MA_ROWS * 75 + 255) / 256;
    int mean_blocks = (N_MOLS * 75 + 255) / 256;

    // 0) weight prep (tiny)
    prep_w<<<(5  * CHUNKS_B + 255) / 256, blk256, 0, stream>>>(W_i, Wib, BOND_FDIM, 5 * CHUNKS_B);
    prep_w<<<(10 * CHUNKS_B + 255) / 256, blk256, 0, stream>>>(W_h, Whb, HIDDEN, 10 * CHUNKS_B);
    prep_w<<<(14 * CHUNKS_B + 255) / 256, blk256, 0, stream>>>(W_o, Wob, ATOM_FDIM + HIDDEN, 14 * CHUNKS_B);

    // 1) inp = relu(f_bonds @ W_i)
    gemm_mfma<0><<<gb, blk512, 0, stream>>>(
        f_bonds, nullptr, nullptr, nullptr, nullptr,
        Wib, nullptr, nullptr, inp, MB_ROWS, 5);

    // 2) round 0: msgA = relu(inp + (agg -> gather-sub) @ W_h)
    aggregate_k<<<agg_blocks, blk256, 0, stream>>>(inp, a2b, amsg);
    gemm_mfma<1><<<gb, blk512, 0, stream>>>(
        nullptr, amsg, inp, b2a, b2revb,
        Whb, nullptr, inp, msgA, MB_ROWS, 10);

    // 3) round 1: inp = relu(inp + ...) in-place (same-element alias only)
    aggregate_k<<<agg_blocks, blk256, 0, stream>>>(msgA, a2b, amsg);
    gemm_mfma<1><<<gb, blk512, 0, stream>>>(
        nullptr, amsg, msgA, b2a, b2revb,
        Whb, nullptr, inp, inp, MB_ROWS, 10);

    // 4) readout: atom_h (=msgA) = relu([f_atoms | agg(inp)] @ W_o + b_o)
    aggregate_k<<<agg_blocks, blk256, 0, stream>>>(inp, a2b, amsg);
    gemm_mfma<2><<<ga, blk512, 0, stream>>>(
        f_atoms, amsg, nullptr, nullptr, nullptr,
        Wob, b_o, nullptr, msgA, MA_ROWS, 14);

    // 5) per-molecule mean
    mol_mean_k<<<mean_blocks, blk256, 0, stream>>>(msgA, out);
}

// Round 2
// 947.080 us; speedup vs baseline: 1.2737x; 1.2672x over previous
//
#include <hip/hip_runtime.h>
#include <hip/hip_bf16.h>

// Problem constants (fixed by reference setup_inputs)
#define N_ATOMS   100000
#define N_BONDS   200000
#define MAX_NB    6
#define HIDDEN    300
#define ATOM_FDIM 133
#define BOND_FDIM 147
#define N_MOLS    5000
#define APM       20      // atoms per mol

#define MB_ROWS (N_BONDS + 1)   // 200001
#define MA_ROWS (N_ATOMS + 1)   // 100001

#define CHUNKS_B 1280     // 16B chunks per k-block image: 4*320*8 bf16 = 20480 B
#define EPS      308      // epilogue LDS row stride in floats (300 cols + pad)

typedef unsigned short bf16_t;
typedef __attribute__((ext_vector_type(8))) __bf16 bf16x8;   // MFMA A/B frag
typedef __attribute__((ext_vector_type(4))) float  float4v;  // MFMA C/D frag

__device__ __forceinline__ float bf2f(unsigned short u) {
    union { unsigned int i; float f; } x; x.i = ((unsigned int)u) << 16; return x.f;
}
__device__ __forceinline__ unsigned short f2bf(float f) {
    union { float f; unsigned int i; } x; x.f = f;
    unsigned int r = x.i + 0x7FFFu + ((x.i >> 16) & 1u);   // RNE (finite values)
    return (unsigned short)(r >> 16);
}

// ===========================================================================
// Weight prep: W fp32 [K][300] row-major -> bf16 k-block images. Chunk c of
// block kb holds, for q=c/320, col=c%320: W[kb*32+q*8+j][col], j=0..7.
// Layout is BOTH the old Bs-LDS image AND directly fragment-addressable:
// fragment (kb, q, col) = 16B at elem ((kb*1280 + q*320 + col)*8).
// ===========================================================================
__global__ __launch_bounds__(256) void prep_w(
    const float* __restrict__ W, bf16_t* __restrict__ dst, int K, int total_chunks)
{
    int idx = blockIdx.x * 256 + threadIdx.x;
    if (idx >= total_chunks) return;
    int kb  = idx / CHUNKS_B;
    int c   = idx - kb * CHUNKS_B;
    int cq  = c / 320;
    int col = c - cq * 320;
    unsigned short v[8];
    #pragma unroll
    for (int j = 0; j < 8; ++j) {
        int k = kb * 32 + cq * 8 + j;
        float f = (k < K && col < HIDDEN) ? W[(size_t)k * HIDDEN + col] : 0.f;
        v[j] = f2bf(f);
    }
    bf16_t* p = dst + (size_t)idx * 8;
    *(ushort4*)(p)     = make_ushort4(v[0], v[1], v[2], v[3]);
    *(ushort4*)(p + 4) = make_ushort4(v[4], v[5], v[6], v[7]);
}

// ===========================================================================
// Full-A-panel MFMA GEMM (r2 redesign):
//   - Block prologue gathers the ENTIRE A-panel (64 rows x full K) into LDS
//     once, with CONTIGUOUS 600B-per-row reads (fixes the 64B-granule random
//     re-gather that bounded r0/r1), as thousands of independent loads.
//   - k-loop has NO barriers and NO B staging: A frags from read-only LDS,
//     B frags loaded straight from the pre-blocked global image (coalesced
//     16B/lane, L1/L2-hot 20KB slice per k-step). Waves run free.
//   - LDS layout As[qg][64][8], qg = kb*4+q; fragment = one contiguous 16B.
//     Maps (verified r5/r6): A m=lane&15, k=q*8+j; B n=lane&15, k=q*8+j;
//     C/D col=lane&15, row=q*4+reg.
// Block: 512 thr = 8 waves (2m x 4n); tile 64(m) x 320(n); wave 32m x 80n;
// acc[2][5] = 40 VGPR; __launch_bounds__(512,4) -> 4 waves/SIMD.
// MODE 0: A = f_bonds fp32 [M,147];            Y = relu(A@W)
// MODE 1: A = amsg[b2a[r]] - cur[b2revb[r]];   Y = relu(addend + A@W)
//         (Y may alias addend: same-element read-before-write only)
// MODE 2: A = [f_atoms fp32 (133) | amsg bf16 (300)]; Y = relu(A@W + bias)
// ===========================================================================
template<int MODE, int KB>
__global__ __launch_bounds__(512, 4) void gemm_mfma(
    const float* __restrict__ Af,
    const bf16_t* __restrict__ Ab1, const bf16_t* __restrict__ Ab2,
    const int* __restrict__ b2a, const int* __restrict__ b2revb,
    const bf16_t* __restrict__ WB, const float* __restrict__ bias,
    const bf16_t* __restrict__ addend, bf16_t* __restrict__ Y,
    int M)
{
    const int S = HIDDEN;   // output row stride 300
    constexpr int QG = KB * 4;                       // 8-col k-groups per row
    constexpr int LDS_BYTES = (KB * 4096 > 16 * EPS * 4) ? KB * 4096 : 16 * EPS * 4;
    __shared__ __align__(16) char lds_pool[LDS_BYTES];
    bf16_t* As  = (bf16_t*)lds_pool;                 // [QG][64][8]
    float*  epi = (float*)lds_pool;                  // epilogue reuse
    __shared__ int rowmap[128];                      // MODE1: b2a | b2revb

    const int tid  = threadIdx.x;
    const int lane = tid & 63;
    const int w    = tid >> 6;        // 0..7
    const int wm   = w >> 2;          // m-half (0/1): 32 rows
    const int wn   = w & 3;           // n-quarter (0..3): 80 cols
    const int lrow = lane & 15;
    const int q    = lane >> 4;       // quad 0..3
    const int bm   = blockIdx.x * 64;

    // ---- MODE1: cache the per-row gather indices -------------------------
    if (MODE == 1) {
        if (tid < 64) {
            int sr = bm + tid;
            rowmap[tid] = (sr < M) ? b2a[sr] : 0;          // row 0 is all-zero
        } else if (tid < 128) {
            int sr = bm + tid - 64;
            rowmap[tid] = (sr < M) ? b2revb[sr] : 0;
        }
        __syncthreads();
    }

    // ---- stage FULL A-panel: 64 rows x K, contiguous-per-row reads -------
    // task t -> (row = t/QG, qg = t%QG): 8 k-elems, one 16B LDS store.
    // Consecutive threads walk consecutive 16B chunks of the same row.
    for (int t = tid; t < 64 * QG; t += 512) {
        int row = t / QG;
        int qg  = t - row * QG;
        int k0  = qg * 8;
        unsigned short av[8];
        if (MODE == 1) {
            const bf16_t* pa = Ab1 + (size_t)rowmap[row]      * S;
            const bf16_t* pc = Ab2 + (size_t)rowmap[64 + row] * S;
            if (k0 + 8 <= S) {
                ushort4 a0 = *(const ushort4*)(pa + k0);
                ushort4 a1 = *(const ushort4*)(pa + k0 + 4);
                ushort4 c0 = *(const ushort4*)(pc + k0);
                ushort4 c1 = *(const ushort4*)(pc + k0 + 4);
                av[0] = f2bf(bf2f(a0.x) - bf2f(c0.x));
                av[1] = f2bf(bf2f(a0.y) - bf2f(c0.y));
                av[2] = f2bf(bf2f(a0.z) - bf2f(c0.z));
                av[3] = f2bf(bf2f(a0.w) - bf2f(c0.w));
                av[4] = f2bf(bf2f(a1.x) - bf2f(c1.x));
                av[5] = f2bf(bf2f(a1.y) - bf2f(c1.y));
                av[6] = f2bf(bf2f(a1.z) - bf2f(c1.z));
                av[7] = f2bf(bf2f(a1.w) - bf2f(c1.w));
            } else {
                #pragma unroll
                for (int j = 0; j < 8; ++j) {
                    int k = k0 + j;
                    av[j] = (k < S) ? f2bf(bf2f(pa[k]) - bf2f(pc[k]))
                                    : (unsigned short)0;
                }
            }
        } else if (MODE == 0) {
            int srow = bm + row;
            #pragma unroll
            for (int j = 0; j < 8; ++j) {
                int k = k0 + j;
                av[j] = (srow < M && k < BOND_FDIM)
                        ? f2bf(Af[(size_t)srow * BOND_FDIM + k]) : (unsigned short)0;
            }
        } else {   // MODE 2: [f_atoms(133) | amsg(300)]
            int srow = bm + row;
            #pragma unroll
            for (int j = 0; j < 8; ++j) {
                int k = k0 + j;
                unsigned short u = 0;
                if (srow < M) {
                    if (k < ATOM_FDIM)
                        u = f2bf(Af[(size_t)srow * ATOM_FDIM + k]);
                    else if (k < ATOM_FDIM + HIDDEN)
                        u = Ab1[(size_t)srow * S + (k - ATOM_FDIM)];
                }
                av[j] = u;
            }
        }
        bf16_t* dst = As + (size_t)(qg * 64 + row) * 8;
        *(ushort4*)(dst)     = make_ushort4(av[0], av[1], av[2], av[3]);
        *(ushort4*)(dst + 4) = make_ushort4(av[4], av[5], av[6], av[7]);
    }

    float4v acc[2][5];
    #pragma unroll
    for (int i = 0; i < 2; ++i)
        #pragma unroll
        for (int j = 0; j < 5; ++j) {
            float4v z = {0.f, 0.f, 0.f, 0.f};
            acc[i][j] = z;
        }

    __syncthreads();   // A-panel visible to all waves

    // ---- barrier-free k-loop: A from LDS, B from global (L1/L2-hot) ------
    // per-thread B fragment base within a k-block image:
    const bf16_t* wbase = WB + (size_t)(q * 320 + wn * 80 + lrow) * 8;
    #pragma unroll 2
    for (int kb = 0; kb < KB; ++kb) {
        bf16x8 af0 = *(const bf16x8*)(As + (size_t)((kb * 4 + q) * 64 + wm * 32 + lrow) * 8);
        bf16x8 af1 = *(const bf16x8*)(As + (size_t)((kb * 4 + q) * 64 + wm * 32 + 16 + lrow) * 8);
        const bf16_t* wk = wbase + (size_t)kb * (CHUNKS_B * 8);
        #pragma unroll
        for (int nt = 0; nt < 5; ++nt) {
            const int c0 = wn * 80 + nt * 16;
            if (c0 < HIDDEN) {   // skip the all-pad tile (cols 304..319)
                bf16x8 bfr = *(const bf16x8*)(wk + (size_t)nt * 16 * 8);
                acc[0][nt] = __builtin_amdgcn_mfma_f32_16x16x32_bf16(af0, bfr, acc[0][nt], 0, 0, 0);
                acc[1][nt] = __builtin_amdgcn_mfma_f32_16x16x32_bf16(af1, bfr, acc[1][nt], 0, 0, 0);
            }
        }
    }

    // ---- epilogue: LDS transpose -> coalesced ushort4 rows ---------------
    __syncthreads();   // safe to overwrite As pool
    #pragma unroll
    for (int mt = 0; mt < 2; ++mt) {
        for (int wh = 0; wh < 2; ++wh) {
            if (wm == wh) {
                #pragma unroll
                for (int nt = 0; nt < 5; ++nt) {
                    const int c0 = wn * 80 + nt * 16;
                    if (c0 < HIDDEN) {
                        #pragma unroll
                        for (int r = 0; r < 4; ++r)
                            epi[(q * 4 + r) * EPS + c0 + lrow] = acc[mt][nt][r];
                    }
                }
            }
            __syncthreads();
            const int row0 = bm + wh * 32 + mt * 16;
            for (int s = tid; s < 16 * 75; s += 512) {
                int rr = s / 75;
                int c4 = s - rr * 75;
                int grow = row0 + rr;
                if (grow < M) {
                    float4 v = *(const float4*)&epi[rr * EPS + c4 * 4];
                    if (MODE == 1) {
                        ushort4 ad = *(const ushort4*)(addend + (size_t)grow * S + c4 * 4);
                        v.x += bf2f(ad.x); v.y += bf2f(ad.y);
                        v.z += bf2f(ad.z); v.w += bf2f(ad.w);
                    }
                    if (MODE == 2) {
                        float4 bv = *(const float4*)(bias + c4 * 4);
                        v.x += bv.x; v.y += bv.y; v.z += bv.z; v.w += bv.w;
                    }
                    ushort4 o;
                    o.x = f2bf(v.x > 0.f ? v.x : 0.f);
                    o.y = f2bf(v.y > 0.f ? v.y : 0.f);
                    o.z = f2bf(v.z > 0.f ? v.z : 0.f);
                    o.w = f2bf(v.w > 0.f ? v.w : 0.f);
                    *(ushort4*)(Y + (size_t)grow * S + c4 * 4) = o;
                }
            }
            __syncthreads();   // before next stage overwrites epi
        }
    }
}

// ===========================================================================
// r2/r5-proven: aggregate + mol mean
// ===========================================================================

// amsg[a][:] = sum_j msg[a2b[a][j]][:]   (bf16 in/out, fp32 accumulate)
__global__ __launch_bounds__(256) void aggregate_k(
    const bf16_t* __restrict__ msg, const int* __restrict__ a2b,
    bf16_t* __restrict__ amsg)
{
    int idx = blockIdx.x * blockDim.x + threadIdx.x;
    const int total = MA_ROWS * 75;
    if (idx >= total) return;
    int a  = idx / 75;
    int c4 = idx - a * 75;
    const int* nb = a2b + (size_t)a * MAX_NB;
    float4 s = make_float4(0.f, 0.f, 0.f, 0.f);
    #pragma unroll
    for (int j = 0; j < MAX_NB; ++j) {
        int b = nb[j];
        ushort4 u = *(const ushort4*)(msg + (size_t)b * HIDDEN + c4 * 4);
        s.x += bf2f(u.x); s.y += bf2f(u.y); s.z += bf2f(u.z); s.w += bf2f(u.w);
    }
    ushort4 o;
    o.x = f2bf(s.x); o.y = f2bf(s.y); o.z = f2bf(s.z); o.w = f2bf(s.w);
    *(ushort4*)(amsg + (size_t)a * HIDDEN + c4 * 4) = o;
}

// mol_vecs[m][:] = mean over 20 consecutive atom rows (offset by 1), fp32 out
__global__ __launch_bounds__(256) void mol_mean_k(
    const bf16_t* __restrict__ atom_h, float* __restrict__ out)
{
    int idx = blockIdx.x * blockDim.x + threadIdx.x;
    if (idx >= N_MOLS * 75) return;
    int m  = idx / 75;
    int c4 = idx - m * 75;
    const bf16_t* base = atom_h + (size_t)(1 + m * APM) * HIDDEN + c4 * 4;
    float4 s = make_float4(0.f, 0.f, 0.f, 0.f);
    #pragma unroll
    for (int i = 0; i < APM; ++i) {
        ushort4 u = *(const ushort4*)(base + (size_t)i * HIDDEN);
        s.x += bf2f(u.x); s.y += bf2f(u.y); s.z += bf2f(u.z); s.w += bf2f(u.w);
    }
    const float inv = 1.0f / (float)APM;
    s.x *= inv; s.y *= inv; s.z *= inv; s.w *= inv;
    *(float4*)(out + (size_t)m * HIDDEN + c4 * 4) = s;
}

// ---------------------------------------------------------------------------
extern "C" void kernel_launch(void* const* d_in, const int* in_sizes, int n_in,
                              void* d_out, int out_size, void* d_ws, size_t ws_size,
                              hipStream_t stream)
{
    const float* f_atoms = (const float*)d_in[0];
    const float* f_bonds = (const float*)d_in[1];
    const float* W_i     = (const float*)d_in[2];
    const float* W_h     = (const float*)d_in[3];
    const float* W_o     = (const float*)d_in[4];
    const float* b_o     = (const float*)d_in[5];
    const int*   a2b     = (const int*)d_in[6];
    const int*   b2a     = (const int*)d_in[7];
    const int*   b2revb  = (const int*)d_in[8];
    float* out = (float*)d_out;

    // Workspace: r2/r5/r6-proven layout (300,002,136 B — do NOT grow d_ws!)
    char* base = (char*)d_ws;
    const size_t SZ_BOND_B = (((size_t)MB_ROWS * HIDDEN * sizeof(bf16_t)) + 255) & ~(size_t)255;
    bf16_t* inp  = (bf16_t*)(base);
    bf16_t* msgA = (bf16_t*)(base + SZ_BOND_B);
    bf16_t* amsg = (bf16_t*)(base + 2 * SZ_BOND_B);

    // Pre-blocked bf16 weights live in d_out scratch (6 MB; 593,920 B used).
    // Safe: fully consumed before mol_mean_k overwrites every output element.
    char* scratch = (char*)d_out;
    bf16_t* Wib = (bf16_t*)(scratch);                 //  5 kb * 20480 B = 102,400
    bf16_t* Whb = (bf16_t*)(scratch + 102400);        // 10 kb           = 204,800
    bf16_t* Wob = (bf16_t*)(scratch + 307200);        // 14 kb           = 286,720

    dim3 blk512(512), blk256(256);
    const int gb = (MB_ROWS + 63) / 64;   // 3126
    const int ga = (MA_ROWS + 63) / 64;   // 1563
    int agg_blocks  = (MA_ROWS * 75 + 255) / 256;
    int mean_blocks = (N_MOLS * 75 + 255) / 256;

    // 0) weight prep (tiny)
    prep_w<<<(5  * CHUNKS_B + 255) / 256, blk256, 0, stream>>>(W_i, Wib, BOND_FDIM, 5 * CHUNKS_B);
    prep_w<<<(10 * CHUNKS_B + 255) / 256, blk256, 0, stream>>>(W_h, Whb, HIDDEN, 10 * CHUNKS_B);
    prep_w<<<(14 * CHUNKS_B + 255) / 256, blk256, 0, stream>>>(W_o, Wob, ATOM_FDIM + HIDDEN, 14 * CHUNKS_B);

    // 1) inp = relu(f_bonds @ W_i)
    gemm_mfma<0, 5><<<gb, blk512, 0, stream>>>(
        f_bonds, nullptr, nullptr, nullptr, nullptr,
        Wib, nullptr, nullptr, inp, MB_ROWS);

    // 2) round 0: msgA = relu(inp + (agg -> gather-sub) @ W_h)
    aggregate_k<<<agg_blocks, blk256, 0, stream>>>(inp, a2b, amsg);
    gemm_mfma<1, 10><<<gb, blk512, 0, stream>>>(
        nullptr, amsg, inp, b2a, b2revb,
        Whb, nullptr, inp, msgA, MB_ROWS);

    // 3) round 1: inp = relu(inp + ...) in-place (same-element alias only)
    aggregate_k<<<agg_blocks, blk256, 0, stream>>>(msgA, a2b, amsg);
    gemm_mfma<1, 10><<<gb, blk512, 0, stream>>>(
        nullptr, amsg, msgA, b2a, b2revb,
        Whb, nullptr, inp, inp, MB_ROWS);

    // 4) readout: atom_h (=msgA) = relu([f_atoms | agg(inp)] @ W_o + b_o)
    aggregate_k<<<agg_blocks, blk256, 0, stream>>>(inp, a2b, amsg);
    gemm_mfma<2, 14><<<ga, blk512, 0, stream>>>(
        f_atoms, amsg, nullptr, nullptr, nullptr,
        Wob, b_o, nullptr, msgA, MA_ROWS);

    // 5) per-molecule mean
    mol_mean_k<<<mean_blocks, blk256, 0, stream>>>(msgA, out);
}

// Round 3
// 849.392 us; speedup vs baseline: 1.4202x; 1.1150x over previous
//
#include <hip/hip_runtime.h>
#include <hip/hip_bf16.h>

// Problem constants (fixed by reference setup_inputs)
#define N_ATOMS   100000
#define N_BONDS   200000
#define MAX_NB    6
#define HIDDEN    300
#define ATOM_FDIM 133
#define BOND_FDIM 147
#define N_MOLS    5000
#define APM       20      // atoms per mol

#define MB_ROWS (N_BONDS + 1)   // 200001
#define MA_ROWS (N_ATOMS + 1)   // 100001

#define CHUNKS_B 1280     // 16B chunks per k-block image: 4*320*8 bf16 = 20480 B
#define EPS      308      // epilogue LDS row stride in floats (300 cols + pad)
#define ROWP     65       // padded A-panel rows per qg (64 + 1): bank-uniform

typedef unsigned short bf16_t;
typedef __attribute__((ext_vector_type(8))) __bf16 bf16x8;   // MFMA A/B frag
typedef __attribute__((ext_vector_type(4))) float  float4v;  // MFMA C/D frag

__device__ __forceinline__ float bf2f(unsigned short u) {
    union { unsigned int i; float f; } x; x.i = ((unsigned int)u) << 16; return x.f;
}
__device__ __forceinline__ unsigned short f2bf(float f) {
    union { float f; unsigned int i; } x; x.f = f;
    unsigned int r = x.i + 0x7FFFu + ((x.i >> 16) & 1u);   // RNE (finite values)
    return (unsigned short)(r >> 16);
}

// ===========================================================================
// Weight prep: W fp32 -> bf16 k-block images. Chunk c of block kb holds, for
// q=c/320, col=c%320: Wv[kb*32+q*8+j][col], j=0..7 (zero-padded).
// perm=0: Wv[k] = W[k] for k<K.
// perm=1 (MODE2 image): virtual K layout [f_atoms 0..132 | pad 133..135 |
//         amsg 136..435] -> Wv[k] = W[k] (k<133), 0 (133..135), W[k-3]
//         (136..435), 0 beyond. Matches the MODE2 A-panel layout.
// ===========================================================================
__global__ __launch_bounds__(256) void prep_w(
    const float* __restrict__ W, bf16_t* __restrict__ dst, int K,
    int total_chunks, int perm)
{
    int idx = blockIdx.x * 256 + threadIdx.x;
    if (idx >= total_chunks) return;
    int kb  = idx / CHUNKS_B;
    int c   = idx - kb * CHUNKS_B;
    int cq  = c / 320;
    int col = c - cq * 320;
    unsigned short v[8];
    #pragma unroll
    for (int j = 0; j < 8; ++j) {
        int k = kb * 32 + cq * 8 + j;
        int ksrc;
        if (perm) ksrc = (k < 133) ? k : ((k >= 136 && k < 436) ? k - 3 : -1);
        else      ksrc = (k < K) ? k : -1;
        float f = (ksrc >= 0 && col < HIDDEN) ? W[(size_t)ksrc * HIDDEN + col] : 0.f;
        v[j] = f2bf(f);
    }
    bf16_t* p = dst + (size_t)idx * 8;
    *(ushort4*)(p)     = make_ushort4(v[0], v[1], v[2], v[3]);
    *(ushort4*)(p + 4) = make_ushort4(v[4], v[5], v[6], v[7]);
}

// ===========================================================================
// Full-A-panel MFMA GEMM, r3 revision:
//   - staging = two fully-unrolled phases: (1) batch-issue ALL gather loads
//     into static register arrays (one latency round, not NT serial rounds),
//     (2) convert + ds_write.
//   - As padded: index (qg*65 + row)*8 -> stride 1040 B == 1 mod 8 in 16B
//     quads: staging writes AND fragment reads bank-uniform (was 40-way).
//   - k-loop: fully unrolled, B fragments double-buffered in registers
//     (load kb+1 while MFMA on kb); no barriers, no B LDS staging.
// Maps (verified r5/r6): A m=lane&15, k=q*8+j; B n=lane&15, k=q*8+j;
// C/D col=lane&15, row=q*4+reg.
// Block: 512 thr = 8 waves (2m x 4n); tile 64(m) x 320(n); wave 32m x 80n.
// MODE 0: A = f_bonds fp32 [M,147];            Y = relu(A@W)
// MODE 1: A = amsg[b2a[r]] - cur[b2revb[r]];   Y = relu(addend + A@W)
// MODE 2: A = [f_atoms(133)+pad3 | amsg(300)]; Y = relu(A@W + bias)
//         (uses the perm=1 weight image; K boundary at 136)
// ===========================================================================
template<int MODE, int KB>
__global__ __launch_bounds__(512, 4) void gemm_mfma(
    const float* __restrict__ Af,
    const bf16_t* __restrict__ Ab1, const bf16_t* __restrict__ Ab2,
    const int* __restrict__ b2a, const int* __restrict__ b2revb,
    const bf16_t* __restrict__ WB, const float* __restrict__ bias,
    const bf16_t* __restrict__ addend, bf16_t* __restrict__ Y,
    int M)
{
    const int S = HIDDEN;   // output row stride 300
    constexpr int QG = KB * 4;                       // 8-col k-groups per row
    constexpr int NT = (64 * QG + 511) / 512;        // staging tasks/thread
    constexpr int ASZ = QG * ROWP * 16;              // A-panel bytes (padded)
    constexpr int LDS_BYTES = (ASZ > 16 * EPS * 4) ? ASZ : 16 * EPS * 4;
    __shared__ __align__(16) char lds_pool[LDS_BYTES];
    bf16_t* As  = (bf16_t*)lds_pool;                 // [(qg*65+row)*8]
    float*  epi = (float*)lds_pool;                  // epilogue reuse
    __shared__ int rowmap[128];                      // MODE1: b2a | b2revb

    const int tid  = threadIdx.x;
    const int lane = tid & 63;
    const int w    = tid >> 6;        // 0..7
    const int wm   = w >> 2;          // m-half (0/1): 32 rows
    const int wn   = w & 3;           // n-quarter (0..3): 80 cols
    const int lrow = lane & 15;
    const int q    = lane >> 4;       // quad 0..3
    const int bm   = blockIdx.x * 64;

    // ---- MODE1: cache the per-row gather indices -------------------------
    if (MODE == 1) {
        if (tid < 64) {
            int sr = bm + tid;
            rowmap[tid] = (sr < M) ? b2a[sr] : 0;          // row 0 is all-zero
        } else if (tid < 128) {
            int sr = bm + tid - 64;
            rowmap[tid] = (sr < M) ? b2revb[sr] : 0;
        }
        __syncthreads();
    }

    // ---- staging phase 1: batch-issue ALL loads (static-indexed arrays) --
    ushort4 A0[NT], A1[NT], C0[NT], C1[NT];   // MODE1
    float   F[(MODE == 1) ? 1 : NT][8];       // MODE0/2 (bf16 packed via cast)
    const ushort4 zz = make_ushort4(0, 0, 0, 0);

    #pragma unroll
    for (int i = 0; i < NT; ++i) {
        int t = tid + i * 512;
        if (t < 64 * QG) {
            int row = t / QG;
            int qg  = t - row * QG;
            int k0  = qg * 8;
            if (MODE == 1) {
                const bf16_t* pa = Ab1 + (size_t)rowmap[row]      * S;
                const bf16_t* pc = Ab2 + (size_t)rowmap[64 + row] * S;
                A0[i] = (k0 + 4 <= S) ? *(const ushort4*)(pa + k0)     : zz;
                A1[i] = (k0 + 8 <= S) ? *(const ushort4*)(pa + k0 + 4) : zz;
                C0[i] = (k0 + 4 <= S) ? *(const ushort4*)(pc + k0)     : zz;
                C1[i] = (k0 + 8 <= S) ? *(const ushort4*)(pc + k0 + 4) : zz;
            } else if (MODE == 0) {
                int srow = bm + row;
                #pragma unroll
                for (int j = 0; j < 8; ++j) {
                    int k = k0 + j;
                    F[i][j] = (srow < M && k < BOND_FDIM)
                              ? Af[(size_t)srow * BOND_FDIM + k] : 0.f;
                }
            } else {   // MODE 2: k' layout [f_atoms 0..132 | pad | amsg 136..435]
                int srow = bm + row;
                if (k0 < 136) {          // pure fp32 region (incl. pad cols)
                    #pragma unroll
                    for (int j = 0; j < 8; ++j) {
                        int k = k0 + j;
                        F[i][j] = (srow < M && k < ATOM_FDIM)
                                  ? Af[(size_t)srow * ATOM_FDIM + k] : 0.f;
                    }
                } else {                 // pure bf16 region, 8-elem aligned
                    int off = k0 - 136;
                    const bf16_t* pm = Ab1 + (size_t)srow * S;
                    ushort4 u0 = (srow < M && off + 4 <= S)
                                 ? *(const ushort4*)(pm + off)     : zz;
                    ushort4 u1 = (srow < M && off + 8 <= S)
                                 ? *(const ushort4*)(pm + off + 4) : zz;
                    *(ushort4*)&F[i][0] = u0;    // pack raw bf16 in float slots
                    *(ushort4*)&F[i][2] = u1;
                }
            }
        }
    }

    // ---- staging phase 2: convert + ds_write (bank-uniform, padded) ------
    #pragma unroll
    for (int i = 0; i < NT; ++i) {
        int t = tid + i * 512;
        if (t < 64 * QG) {
            int row = t / QG;
            int qg  = t - row * QG;
            unsigned short av[8];
            if (MODE == 1) {
                av[0] = f2bf(bf2f(A0[i].x) - bf2f(C0[i].x));
                av[1] = f2bf(bf2f(A0[i].y) - bf2f(C0[i].y));
                av[2] = f2bf(bf2f(A0[i].z) - bf2f(C0[i].z));
                av[3] = f2bf(bf2f(A0[i].w) - bf2f(C0[i].w));
                av[4] = f2bf(bf2f(A1[i].x) - bf2f(C1[i].x));
                av[5] = f2bf(bf2f(A1[i].y) - bf2f(C1[i].y));
                av[6] = f2bf(bf2f(A1[i].z) - bf2f(C1[i].z));
                av[7] = f2bf(bf2f(A1[i].w) - bf2f(C1[i].w));
            } else if (MODE == 0) {
                #pragma unroll
                for (int j = 0; j < 8; ++j) av[j] = f2bf(F[i][j]);
            } else {
                int k0 = qg * 8;
                if (k0 < 136) {
                    #pragma unroll
                    for (int j = 0; j < 8; ++j) av[j] = f2bf(F[i][j]);
                } else {
                    ushort4 u0 = *(const ushort4*)&F[i][0];
                    ushort4 u1 = *(const ushort4*)&F[i][2];
                    av[0] = u0.x; av[1] = u0.y; av[2] = u0.z; av[3] = u0.w;
                    av[4] = u1.x; av[5] = u1.y; av[6] = u1.z; av[7] = u1.w;
                }
            }
            bf16_t* dst = As + (size_t)(qg * ROWP + row) * 8;
            *(ushort4*)(dst)     = make_ushort4(av[0], av[1], av[2], av[3]);
            *(ushort4*)(dst + 4) = make_ushort4(av[4], av[5], av[6], av[7]);
        }
    }

    float4v acc[2][5];
    #pragma unroll
    for (int i = 0; i < 2; ++i)
        #pragma unroll
        for (int j = 0; j < 5; ++j) {
            float4v z = {0.f, 0.f, 0.f, 0.f};
            acc[i][j] = z;
        }

    __syncthreads();   // A-panel visible to all waves

    // ---- barrier-free k-loop: A from LDS, B double-buffered from global --
    const bf16_t* wptr = WB + (size_t)(q * 320 + wn * 80 + lrow) * 8;
    bf16x8 bcur[5], bnxt[5];
    #pragma unroll
    for (int nt = 0; nt < 5; ++nt)
        bcur[nt] = *(const bf16x8*)(wptr + nt * 128);

    #pragma unroll
    for (int kb = 0; kb < KB; ++kb) {
        const bf16_t* abase = As + (size_t)((kb * 4 + q) * ROWP + wm * 32 + lrow) * 8;
        bf16x8 af0 = *(const bf16x8*)(abase);
        bf16x8 af1 = *(const bf16x8*)(abase + 16 * 8);   // +16 rows
        if (kb + 1 < KB) {
            const bf16_t* wnx = wptr + (size_t)(kb + 1) * (CHUNKS_B * 8);
            #pragma unroll
            for (int nt = 0; nt < 5; ++nt)
                bnxt[nt] = *(const bf16x8*)(wnx + nt * 128);
        }
        #pragma unroll
        for (int nt = 0; nt < 5; ++nt) {
            if (wn * 80 + nt * 16 < HIDDEN) {   // skip all-pad tile (cols 304+)
                acc[0][nt] = __builtin_amdgcn_mfma_f32_16x16x32_bf16(af0, bcur[nt], acc[0][nt], 0, 0, 0);
                acc[1][nt] = __builtin_amdgcn_mfma_f32_16x16x32_bf16(af1, bcur[nt], acc[1][nt], 0, 0, 0);
            }
        }
        if (kb + 1 < KB) {
            #pragma unroll
            for (int nt = 0; nt < 5; ++nt) bcur[nt] = bnxt[nt];
        }
    }

    // ---- epilogue: LDS transpose -> coalesced ushort4 rows ---------------
    __syncthreads();   // safe to overwrite As pool
    #pragma unroll
    for (int mt = 0; mt < 2; ++mt) {
        for (int wh = 0; wh < 2; ++wh) {
            if (wm == wh) {
                #pragma unroll
                for (int nt = 0; nt < 5; ++nt) {
                    const int c0 = wn * 80 + nt * 16;
                    if (c0 < HIDDEN) {
                        #pragma unroll
                        for (int r = 0; r < 4; ++r)
                            epi[(q * 4 + r) * EPS + c0 + lrow] = acc[mt][nt][r];
                    }
                }
            }
            __syncthreads();
            const int row0 = bm + wh * 32 + mt * 16;
            for (int s = tid; s < 16 * 75; s += 512) {
                int rr = s / 75;
                int c4 = s - rr * 75;
                int grow = row0 + rr;
                if (grow < M) {
                    float4 v = *(const float4*)&epi[rr * EPS + c4 * 4];
                    if (MODE == 1) {
                        ushort4 ad = *(const ushort4*)(addend + (size_t)grow * S + c4 * 4);
                        v.x += bf2f(ad.x); v.y += bf2f(ad.y);
                        v.z += bf2f(ad.z); v.w += bf2f(ad.w);
                    }
                    if (MODE == 2) {
                        float4 bv = *(const float4*)(bias + c4 * 4);
                        v.x += bv.x; v.y += bv.y; v.z += bv.z; v.w += bv.w;
                    }
                    ushort4 o;
                    o.x = f2bf(v.x > 0.f ? v.x : 0.f);
                    o.y = f2bf(v.y > 0.f ? v.y : 0.f);
                    o.z = f2bf(v.z > 0.f ? v.z : 0.f);
                    o.w = f2bf(v.w > 0.f ? v.w : 0.f);
                    *(ushort4*)(Y + (size_t)grow * S + c4 * 4) = o;
                }
            }
            __syncthreads();   // before next stage overwrites epi
        }
    }
}

// ===========================================================================
// aggregate: amsg[a][:] = sum_j msg[a2b[a][j]][:]  (bf16, fp32 accumulate)
// r3: 12 cols/thread -> 18 row-loads in flight (was 6), 3x fewer threads.
// ===========================================================================
__global__ __launch_bounds__(256) void aggregate_k(
    const bf16_t* __restrict__ msg, const int* __restrict__ a2b,
    bf16_t* __restrict__ amsg)
{
    int idx = blockIdx.x * blockDim.x + threadIdx.x;
    const int total = MA_ROWS * 25;
    if (idx >= total) return;
    int a  = idx / 25;
    int g  = idx - a * 25;
    int c0 = g * 12;
    const int* nb = a2b + (size_t)a * MAX_NB;
    int b[MAX_NB];
    #pragma unroll
    for (int j = 0; j < MAX_NB; ++j) b[j] = nb[j];
    ushort4 u0[MAX_NB], u1[MAX_NB], u2[MAX_NB];
    #pragma unroll
    for (int j = 0; j < MAX_NB; ++j) {
        const bf16_t* p = msg + (size_t)b[j] * HIDDEN + c0;
        u0[j] = *(const ushort4*)(p);
        u1[j] = *(const ushort4*)(p + 4);
        u2[j] = *(const ushort4*)(p + 8);
    }
    float s[12];
    #pragma unroll
    for (int k = 0; k < 12; ++k) s[k] = 0.f;
    #pragma unroll
    for (int j = 0; j < MAX_NB; ++j) {
        s[0] += bf2f(u0[j].x); s[1]  += bf2f(u0[j].y);
        s[2] += bf2f(u0[j].z); s[3]  += bf2f(u0[j].w);
        s[4] += bf2f(u1[j].x); s[5]  += bf2f(u1[j].y);
        s[6] += bf2f(u1[j].z); s[7]  += bf2f(u1[j].w);
        s[8] += bf2f(u2[j].x); s[9]  += bf2f(u2[j].y);
        s[10]+= bf2f(u2[j].z); s[11] += bf2f(u2[j].w);
    }
    bf16_t* o = amsg + (size_t)a * HIDDEN + c0;
    *(ushort4*)(o)     = make_ushort4(f2bf(s[0]), f2bf(s[1]), f2bf(s[2]),  f2bf(s[3]));
    *(ushort4*)(o + 4) = make_ushort4(f2bf(s[4]), f2bf(s[5]), f2bf(s[6]),  f2bf(s[7]));
    *(ushort4*)(o + 8) = make_ushort4(f2bf(s[8]), f2bf(s[9]), f2bf(s[10]), f2bf(s[11]));
}

// mol_vecs[m][:] = mean over 20 consecutive atom rows (offset by 1), fp32 out
__global__ __launch_bounds__(256) void mol_mean_k(
    const bf16_t* __restrict__ atom_h, float* __restrict__ out)
{
    int idx = blockIdx.x * blockDim.x + threadIdx.x;
    if (idx >= N_MOLS * 75) return;
    int m  = idx / 75;
    int c4 = idx - m * 75;
    const bf16_t* base = atom_h + (size_t)(1 + m * APM) * HIDDEN + c4 * 4;
    float4 s = make_float4(0.f, 0.f, 0.f, 0.f);
    #pragma unroll
    for (int i = 0; i < APM; ++i) {
        ushort4 u = *(const ushort4*)(base + (size_t)i * HIDDEN);
        s.x += bf2f(u.x); s.y += bf2f(u.y); s.z += bf2f(u.z); s.w += bf2f(u.w);
    }
    const float inv = 1.0f / (float)APM;
    s.x *= inv; s.y *= inv; s.z *= inv; s.w *= inv;
    *(float4*)(out + (size_t)m * HIDDEN + c4 * 4) = s;
}

// ---------------------------------------------------------------------------
extern "C" void kernel_launch(void* const* d_in, const int* in_sizes, int n_in,
                              void* d_out, int out_size, void* d_ws, size_t ws_size,
                              hipStream_t stream)
{
    const float* f_atoms = (const float*)d_in[0];
    const float* f_bonds = (const float*)d_in[1];
    const float* W_i     = (const float*)d_in[2];
    const float* W_h     = (const float*)d_in[3];
    const float* W_o     = (const float*)d_in[4];
    const float* b_o     = (const float*)d_in[5];
    const int*   a2b     = (const int*)d_in[6];
    const int*   b2a     = (const int*)d_in[7];
    const int*   b2revb  = (const int*)d_in[8];
    float* out = (float*)d_out;

    // Workspace: r2/r5/r6-proven layout (300,002,136 B — do NOT grow d_ws!)
    char* base = (char*)d_ws;
    const size_t SZ_BOND_B = (((size_t)MB_ROWS * HIDDEN * sizeof(bf16_t)) + 255) & ~(size_t)255;
    bf16_t* inp  = (bf16_t*)(base);
    bf16_t* msgA = (bf16_t*)(base + SZ_BOND_B);
    bf16_t* amsg = (bf16_t*)(base + 2 * SZ_BOND_B);

    // Pre-blocked bf16 weights live in d_out scratch (6 MB; 593,920 B used).
    // Safe: fully consumed before mol_mean_k overwrites every output element.
    char* scratch = (char*)d_out;
    bf16_t* Wib = (bf16_t*)(scratch);                 //  5 kb * 20480 B = 102,400
    bf16_t* Whb = (bf16_t*)(scratch + 102400);        // 10 kb           = 204,800
    bf16_t* Wob = (bf16_t*)(scratch + 307200);        // 14 kb           = 286,720

    dim3 blk512(512), blk256(256);
    const int gb = (MB_ROWS + 63) / 64;   // 3126
    const int ga = (MA_ROWS + 63) / 64;   // 1563
    int agg_blocks  = (MA_ROWS * 25 + 255) / 256;
    int mean_blocks = (N_MOLS * 75 + 255) / 256;

    // 0) weight prep (tiny)
    prep_w<<<(5  * CHUNKS_B + 255) / 256, blk256, 0, stream>>>(W_i, Wib, BOND_FDIM, 5 * CHUNKS_B, 0);
    prep_w<<<(10 * CHUNKS_B + 255) / 256, blk256, 0, stream>>>(W_h, Whb, HIDDEN, 10 * CHUNKS_B, 0);
    prep_w<<<(14 * CHUNKS_B + 255) / 256, blk256, 0, stream>>>(W_o, Wob, 436, 14 * CHUNKS_B, 1);

    // 1) inp = relu(f_bonds @ W_i)
    gemm_mfma<0, 5><<<gb, blk512, 0, stream>>>(
        f_bonds, nullptr, nullptr, nullptr, nullptr,
        Wib, nullptr, nullptr, inp, MB_ROWS);

    // 2) round 0: msgA = relu(inp + (agg -> gather-sub) @ W_h)
    aggregate_k<<<agg_blocks, blk256, 0, stream>>>(inp, a2b, amsg);
    gemm_mfma<1, 10><<<gb, blk512, 0, stream>>>(
        nullptr, amsg, inp, b2a, b2revb,
        Whb, nullptr, inp, msgA, MB_ROWS);

    // 3) round 1: inp = relu(inp + ...) in-place (same-element alias only)
    aggregate_k<<<agg_blocks, blk256, 0, stream>>>(msgA, a2b, amsg);
    gemm_mfma<1, 10><<<gb, blk512, 0, stream>>>(
        nullptr, amsg, msgA, b2a, b2revb,
        Whb, nullptr, inp, inp, MB_ROWS);

    // 4) readout: atom_h (=msgA) = relu([f_atoms | agg(inp)] @ W_o + b_o)
    aggregate_k<<<agg_blocks, blk256, 0, stream>>>(inp, a2b, amsg);
    gemm_mfma<2, 14><<<ga, blk512, 0, stream>>>(
        f_atoms, amsg, nullptr, nullptr, nullptr,
        Wob, b_o, nullptr, msgA, MA_ROWS);

    // 5) per-molecule mean
    mol_mean_k<<<mean_blocks, blk256, 0, stream>>>(msgA, out);
}

// Round 4
// 817.830 us; speedup vs baseline: 1.4750x; 1.0386x over previous
//
#include <hip/hip_runtime.h>
#include <hip/hip_bf16.h>

// Problem constants (fixed by reference setup_inputs)
#define N_ATOMS   100000
#define N_BONDS   200000
#define MAX_NB    6
#define HIDDEN    300
#define ATOM_FDIM 133
#define BOND_FDIM 147
#define N_MOLS    5000
#define APM       20      // atoms per mol

#define MB_ROWS (N_BONDS + 1)   // 200001
#define MA_ROWS (N_ATOMS + 1)   // 100001

#define CHUNKS_B 1280     // 16B chunks per k-block image: 4*320*8 bf16 = 20480 B
#define EPS      308      // epilogue LDS row stride in floats (300 cols + pad)
#define ROWP     65       // padded A-panel rows per qg (64 + 1)

typedef unsigned short bf16_t;
typedef __attribute__((ext_vector_type(8))) __bf16 bf16x8;   // MFMA A/B frag
typedef __attribute__((ext_vector_type(4))) float  float4v;  // MFMA C/D frag

__device__ __forceinline__ float bf2f(unsigned short u) {
    union { unsigned int i; float f; } x; x.i = ((unsigned int)u) << 16; return x.f;
}
__device__ __forceinline__ unsigned short f2bf(float f) {
    union { float f; unsigned int i; } x; x.f = f;
    unsigned int r = x.i + 0x7FFFu + ((x.i >> 16) & 1u);   // RNE (finite values)
    return (unsigned short)(r >> 16);
}

// ===========================================================================
// Weight prep: W fp32 -> bf16 k-block images. Chunk c of block kb holds, for
// q=c/320, col=c%320: Wv[kb*32+q*8+j][col], j=0..7 (zero-padded).
// perm=0: Wv[k] = W[k] for k<K.
// perm=1 (MODE2 image): virtual K layout [f_atoms 0..132 | pad 133..135 |
//         amsg 136..435] -> Wv[k] = W[k] (k<133), 0 (133..135), W[k-3]
//         (136..435), 0 beyond. Matches the MODE2 A-panel layout.
// ===========================================================================
__global__ __launch_bounds__(256) void prep_w(
    const float* __restrict__ W, bf16_t* __restrict__ dst, int K,
    int total_chunks, int perm)
{
    int idx = blockIdx.x * 256 + threadIdx.x;
    if (idx >= total_chunks) return;
    int kb  = idx / CHUNKS_B;
    int c   = idx - kb * CHUNKS_B;
    int cq  = c / 320;
    int col = c - cq * 320;
    unsigned short v[8];
    #pragma unroll
    for (int j = 0; j < 8; ++j) {
        int k = kb * 32 + cq * 8 + j;
        int ksrc;
        if (perm) ksrc = (k < 133) ? k : ((k >= 136 && k < 436) ? k - 3 : -1);
        else      ksrc = (k < K) ? k : -1;
        float f = (ksrc >= 0 && col < HIDDEN) ? W[(size_t)ksrc * HIDDEN + col] : 0.f;
        v[j] = f2bf(f);
    }
    bf16_t* p = dst + (size_t)idx * 8;
    *(ushort4*)(p)     = make_ushort4(v[0], v[1], v[2], v[3]);
    *(ushort4*)(p + 4) = make_ushort4(v[4], v[5], v[6], v[7]);
}

// ===========================================================================
// Full-A-panel MFMA GEMM, r4 revision:
//   - staging loads are UNCONDITIONAL: out-of-range accesses are redirected
//     (v_cndmask pointer/index select, NO branch) to row 0 of the source,
//     which is all-zero by construction. All ~20 gather loads issue
//     back-to-back -> one latency round, full MLP depth. (r3's ternary
//     loads compiled to 20 divergent branch regions; VGPR=48 proved the
//     batch never formed.)
//   - As padded: (qg*65 + row)*8; k-loop: fully unrolled, B double-buffered
//     in registers straight from the pre-blocked global image; no barriers.
// Maps (verified r5/r6): A m=lane&15, k=q*8+j; B n=lane&15, k=q*8+j;
// C/D col=lane&15, row=q*4+reg.
// Block: 512 thr = 8 waves (2m x 4n); tile 64(m) x 320(n); wave 32m x 80n.
// MODE 0: A = f_bonds fp32 [M,147];            Y = relu(A@W)
// MODE 1: A = amsg[b2a[r]] - cur[b2revb[r]];   Y = relu(addend + A@W)
// MODE 2: A = [f_atoms(133)+pad3 | amsg(300)]; Y = relu(A@W + bias)
// ===========================================================================
template<int MODE, int KB>
__global__ __launch_bounds__(512, 4) void gemm_mfma(
    const float* __restrict__ Af,
    const bf16_t* __restrict__ Ab1, const bf16_t* __restrict__ Ab2,
    const int* __restrict__ b2a, const int* __restrict__ b2revb,
    const bf16_t* __restrict__ WB, const float* __restrict__ bias,
    const bf16_t* __restrict__ addend, bf16_t* __restrict__ Y,
    int M)
{
    const int S = HIDDEN;   // output row stride 300
    constexpr int QG    = KB * 4;                    // 8-col k-groups per row
    constexpr int TASKS = 64 * QG;
    constexpr int NT    = (TASKS + 511) / 512;       // staging tasks/thread
    constexpr int ASZ   = QG * ROWP * 16;            // A-panel bytes (padded)
    constexpr int LDS_BYTES = (ASZ > 16 * EPS * 4) ? ASZ : 16 * EPS * 4;
    __shared__ __align__(16) char lds_pool[LDS_BYTES];
    bf16_t* As  = (bf16_t*)lds_pool;                 // [(qg*65+row)*8]
    float*  epi = (float*)lds_pool;                  // epilogue reuse
    __shared__ int rowmap[128];                      // MODE1: b2a | b2revb

    const int tid  = threadIdx.x;
    const int lane = tid & 63;
    const int w    = tid >> 6;        // 0..7
    const int wm   = w >> 2;          // m-half (0/1): 32 rows
    const int wn   = w & 3;           // n-quarter (0..3): 80 cols
    const int lrow = lane & 15;
    const int q    = lane >> 4;       // quad 0..3
    const int bm   = blockIdx.x * 64;

    // ---- MODE1: cache the per-row gather indices -------------------------
    if (MODE == 1) {
        if (tid < 64) {
            int sr = bm + tid;
            rowmap[tid] = (sr < M) ? b2a[sr] : 0;          // row 0 is all-zero
        } else if (tid < 128) {
            int sr = bm + tid - 64;
            rowmap[tid] = (sr < M) ? b2revb[sr] : 0;
        }
        __syncthreads();
    }

    // task activity: compile-time true except the tail batch of KB=5
    #define ACT(i) ((TASKS % 512 == 0) || (((i) + 1) * 512 <= TASKS) || (tid + (i) * 512 < TASKS))

    // ---- staging phase 1a: branch-free clamped pointers ------------------
    // ---- staging phase 1b: unconditional load batch ----------------------
    ushort4 A0[NT], A1[NT], C0[NT], C1[NT];   // MODE1
    float   F[(MODE == 1) ? 1 : NT][8];       // MODE0/2 (bf16 packed via cast)

    if (MODE == 1) {
        const bf16_t* gA0[NT]; const bf16_t* gA1[NT];
        const bf16_t* gC0[NT]; const bf16_t* gC1[NT];
        #pragma unroll
        for (int i = 0; i < NT; ++i) {
            int t   = tid + i * 512;          // TASKS%512==0 for KB=10: no guard
            int row = t / QG;
            int qg  = t - row * QG;
            int k0  = qg * 8;
            const bf16_t* pa = Ab1 + (size_t)rowmap[row]      * S;
            const bf16_t* pc = Ab2 + (size_t)rowmap[64 + row] * S;
            // clamp to Ab1 row 0 (all-zero) when out of K range: select, no branch
            gA0[i] = (k0 + 4 <= S) ? pa + k0     : Ab1;
            gA1[i] = (k0 + 8 <= S) ? pa + k0 + 4 : Ab1;
            gC0[i] = (k0 + 4 <= S) ? pc + k0     : Ab1;
            gC1[i] = (k0 + 8 <= S) ? pc + k0 + 4 : Ab1;
        }
        #pragma unroll
        for (int i = 0; i < NT; ++i) {
            A0[i] = *(const ushort4*)gA0[i];
            A1[i] = *(const ushort4*)gA1[i];
            C0[i] = *(const ushort4*)gC0[i];
            C1[i] = *(const ushort4*)gC1[i];
        }
    } else if (MODE == 0) {
        #pragma unroll
        for (int i = 0; i < NT; ++i) {
            if (ACT(i)) {
                int t = tid + i * 512;
                int row = t / QG, qg = t - row * QG, k0 = qg * 8;
                int srow = bm + row;
                int base = srow * BOND_FDIM;
                #pragma unroll
                for (int j = 0; j < 8; ++j) {
                    int k = k0 + j;
                    // clamp to f_bonds[0][0] (=0): index select, no branch
                    F[i][j] = Af[(srow < M && k < BOND_FDIM) ? base + k : 0];
                }
            }
        }
    } else {   // MODE 2: k' layout [f_atoms 0..132 | pad | amsg 136..435]
        #pragma unroll
        for (int i = 0; i < NT; ++i) {
            int t = tid + i * 512;            // TASKS%512==0 for KB=14
            int row = t / QG, qg = t - row * QG, k0 = qg * 8;
            int srow = bm + row;
            if (k0 < 136) {                   // fp32 region (streaming rows)
                int base = srow * ATOM_FDIM;
                #pragma unroll
                for (int j = 0; j < 8; ++j) {
                    int k = k0 + j;
                    F[i][j] = Af[(srow < M && k < ATOM_FDIM) ? base + k : 0];
                }
            } else {                          // bf16 region, 8-elem aligned
                int off = k0 - 136;
                const bf16_t* pm = Ab1 + (size_t)srow * S;
                const bf16_t* g0 = (srow < M && off + 4 <= S) ? pm + off     : Ab1;
                const bf16_t* g1 = (srow < M && off + 8 <= S) ? pm + off + 4 : Ab1;
                ushort4 u0 = *(const ushort4*)g0;
                ushort4 u1 = *(const ushort4*)g1;
                *(ushort4*)&F[i][0] = u0;     // pack raw bf16 in float slots
                *(ushort4*)&F[i][2] = u1;
            }
        }
    }

    // ---- first B fragments: issued behind the staging batch --------------
    const bf16_t* wptr = WB + (size_t)(q * 320 + wn * 80 + lrow) * 8;
    bf16x8 bcur[5], bnxt[5];
    #pragma unroll
    for (int nt = 0; nt < 5; ++nt)
        bcur[nt] = *(const bf16x8*)(wptr + nt * 128);

    // ---- staging phase 2: convert + ds_write -----------------------------
    #pragma unroll
    for (int i = 0; i < NT; ++i) {
        if (ACT(i)) {
            int t = tid + i * 512;
            int row = t / QG;
            int qg  = t - row * QG;
            unsigned short av[8];
            if (MODE == 1) {
                av[0] = f2bf(bf2f(A0[i].x) - bf2f(C0[i].x));
                av[1] = f2bf(bf2f(A0[i].y) - bf2f(C0[i].y));
                av[2] = f2bf(bf2f(A0[i].z) - bf2f(C0[i].z));
                av[3] = f2bf(bf2f(A0[i].w) - bf2f(C0[i].w));
                av[4] = f2bf(bf2f(A1[i].x) - bf2f(C1[i].x));
                av[5] = f2bf(bf2f(A1[i].y) - bf2f(C1[i].y));
                av[6] = f2bf(bf2f(A1[i].z) - bf2f(C1[i].z));
                av[7] = f2bf(bf2f(A1[i].w) - bf2f(C1[i].w));
            } else if (MODE == 0) {
                #pragma unroll
                for (int j = 0; j < 8; ++j) av[j] = f2bf(F[i][j]);
            } else {
                int k0 = qg * 8;
                if (k0 < 136) {
                    #pragma unroll
                    for (int j = 0; j < 8; ++j) av[j] = f2bf(F[i][j]);
                } else {
                    ushort4 u0 = *(const ushort4*)&F[i][0];
                    ushort4 u1 = *(const ushort4*)&F[i][2];
                    av[0] = u0.x; av[1] = u0.y; av[2] = u0.z; av[3] = u0.w;
                    av[4] = u1.x; av[5] = u1.y; av[6] = u1.z; av[7] = u1.w;
                }
            }
            bf16_t* dst = As + (size_t)(qg * ROWP + row) * 8;
            *(ushort4*)(dst)     = make_ushort4(av[0], av[1], av[2], av[3]);
            *(ushort4*)(dst + 4) = make_ushort4(av[4], av[5], av[6], av[7]);
        }
    }
    #undef ACT

    float4v acc[2][5];
    #pragma unroll
    for (int i = 0; i < 2; ++i)
        #pragma unroll
        for (int j = 0; j < 5; ++j) {
            float4v z = {0.f, 0.f, 0.f, 0.f};
            acc[i][j] = z;
        }

    __syncthreads();   // A-panel visible to all waves

    // ---- barrier-free k-loop: A from LDS, B double-buffered from global --
    #pragma unroll
    for (int kb = 0; kb < KB; ++kb) {
        const bf16_t* abase = As + (size_t)((kb * 4 + q) * ROWP + wm * 32 + lrow) * 8;
        bf16x8 af0 = *(const bf16x8*)(abase);
        bf16x8 af1 = *(const bf16x8*)(abase + 16 * 8);   // +16 rows
        if (kb + 1 < KB) {
            const bf16_t* wnx = wptr + (size_t)(kb + 1) * (CHUNKS_B * 8);
            #pragma unroll
            for (int nt = 0; nt < 5; ++nt)
                bnxt[nt] = *(const bf16x8*)(wnx + nt * 128);
        }
        #pragma unroll
        for (int nt = 0; nt < 5; ++nt) {
            if (wn * 80 + nt * 16 < HIDDEN) {   // skip all-pad tile (cols 304+)
                acc[0][nt] = __builtin_amdgcn_mfma_f32_16x16x32_bf16(af0, bcur[nt], acc[0][nt], 0, 0, 0);
                acc[1][nt] = __builtin_amdgcn_mfma_f32_16x16x32_bf16(af1, bcur[nt], acc[1][nt], 0, 0, 0);
            }
        }
        if (kb + 1 < KB) {
            #pragma unroll
            for (int nt = 0; nt < 5; ++nt) bcur[nt] = bnxt[nt];
        }
    }

    // ---- epilogue: LDS transpose -> coalesced ushort4 rows ---------------
    __syncthreads();   // safe to overwrite As pool
    #pragma unroll
    for (int mt = 0; mt < 2; ++mt) {
        for (int wh = 0; wh < 2; ++wh) {
            if (wm == wh) {
                #pragma unroll
                for (int nt = 0; nt < 5; ++nt) {
                    const int c0 = wn * 80 + nt * 16;
                    if (c0 < HIDDEN) {
                        #pragma unroll
                        for (int r = 0; r < 4; ++r)
                            epi[(q * 4 + r) * EPS + c0 + lrow] = acc[mt][nt][r];
                    }
                }
            }
            __syncthreads();
            const int row0 = bm + wh * 32 + mt * 16;
            for (int s = tid; s < 16 * 75; s += 512) {
                int rr = s / 75;
                int c4 = s - rr * 75;
                int grow = row0 + rr;
                if (grow < M) {
                    float4 v = *(const float4*)&epi[rr * EPS + c4 * 4];
                    if (MODE == 1) {
                        ushort4 ad = *(const ushort4*)(addend + (size_t)grow * S + c4 * 4);
                        v.x += bf2f(ad.x); v.y += bf2f(ad.y);
                        v.z += bf2f(ad.z); v.w += bf2f(ad.w);
                    }
                    if (MODE == 2) {
                        float4 bv = *(const float4*)(bias + c4 * 4);
                        v.x += bv.x; v.y += bv.y; v.z += bv.z; v.w += bv.w;
                    }
                    ushort4 o;
                    o.x = f2bf(v.x > 0.f ? v.x : 0.f);
                    o.y = f2bf(v.y > 0.f ? v.y : 0.f);
                    o.z = f2bf(v.z > 0.f ? v.z : 0.f);
                    o.w = f2bf(v.w > 0.f ? v.w : 0.f);
                    *(ushort4*)(Y + (size_t)grow * S + c4 * 4) = o;
                }
            }
            __syncthreads();   // before next stage overwrites epi
        }
    }
}

// ===========================================================================
// aggregate: amsg[a][:] = sum_j msg[a2b[a][j]][:]  (bf16, fp32 accumulate)
// r4: TWO atom-column-groups per thread -> 12 index + 36 row loads in
// flight (static-indexed register arrays, no branches around loads; the
// second group's indices clamp to atom 0 / row 0, store guarded).
// ===========================================================================
__global__ __launch_bounds__(256, 4) void aggregate_k(
    const bf16_t* __restrict__ msg, const int* __restrict__ a2b,
    bf16_t* __restrict__ amsg)
{
    constexpr int TOT  = MA_ROWS * 25;       // 2,500,025 col-group tasks
    constexpr int HALF = (TOT + 1) / 2;      // 1,250,013
    int i0 = blockIdx.x * 256 + threadIdx.x;
    if (i0 >= HALF) return;
    int  i1   = i0 + HALF;
    bool has1 = (i1 < TOT);
    int  i1c  = has1 ? i1 : 0;               // clamp: atom 0 rows are zero
    int a0 = i0 / 25,  g0 = i0 - a0 * 25,  c0 = g0 * 12;
    int a1 = i1c / 25, g1 = i1c - a1 * 25, c1 = g1 * 12;

    const int* nb0 = a2b + (size_t)a0 * MAX_NB;
    const int* nb1 = a2b + (size_t)a1 * MAX_NB;
    int b0[MAX_NB], b1[MAX_NB];
    #pragma unroll
    for (int j = 0; j < MAX_NB; ++j) { b0[j] = nb0[j]; b1[j] = nb1[j]; }

    ushort4 u0[MAX_NB][3], u1[MAX_NB][3];
    #pragma unroll
    for (int j = 0; j < MAX_NB; ++j) {
        const bf16_t* p = msg + (size_t)b0[j] * HIDDEN + c0;
        u0[j][0] = *(const ushort4*)(p);
        u0[j][1] = *(const ushort4*)(p + 4);
        u0[j][2] = *(const ushort4*)(p + 8);
    }
    #pragma unroll
    for (int j = 0; j < MAX_NB; ++j) {
        const bf16_t* p = msg + (size_t)b1[j] * HIDDEN + c1;
        u1[j][0] = *(const ushort4*)(p);
        u1[j][1] = *(const ushort4*)(p + 4);
        u1[j][2] = *(const ushort4*)(p + 8);
    }

    float s0[12], s1[12];
    #pragma unroll
    for (int k = 0; k < 12; ++k) { s0[k] = 0.f; s1[k] = 0.f; }
    #pragma unroll
    for (int j = 0; j < MAX_NB; ++j) {
        #pragma unroll
        for (int h = 0; h < 3; ++h) {
            s0[h*4+0] += bf2f(u0[j][h].x); s0[h*4+1] += bf2f(u0[j][h].y);
            s0[h*4+2] += bf2f(u0[j][h].z); s0[h*4+3] += bf2f(u0[j][h].w);
            s1[h*4+0] += bf2f(u1[j][h].x); s1[h*4+1] += bf2f(u1[j][h].y);
            s1[h*4+2] += bf2f(u1[j][h].z); s1[h*4+3] += bf2f(u1[j][h].w);
        }
    }
    bf16_t* o0 = amsg + (size_t)a0 * HIDDEN + c0;
    *(ushort4*)(o0)     = make_ushort4(f2bf(s0[0]), f2bf(s0[1]), f2bf(s0[2]),  f2bf(s0[3]));
    *(ushort4*)(o0 + 4) = make_ushort4(f2bf(s0[4]), f2bf(s0[5]), f2bf(s0[6]),  f2bf(s0[7]));
    *(ushort4*)(o0 + 8) = make_ushort4(f2bf(s0[8]), f2bf(s0[9]), f2bf(s0[10]), f2bf(s0[11]));
    if (has1) {
        bf16_t* o1 = amsg + (size_t)a1 * HIDDEN + c1;
        *(ushort4*)(o1)     = make_ushort4(f2bf(s1[0]), f2bf(s1[1]), f2bf(s1[2]),  f2bf(s1[3]));
        *(ushort4*)(o1 + 4) = make_ushort4(f2bf(s1[4]), f2bf(s1[5]), f2bf(s1[6]),  f2bf(s1[7]));
        *(ushort4*)(o1 + 8) = make_ushort4(f2bf(s1[8]), f2bf(s1[9]), f2bf(s1[10]), f2bf(s1[11]));
    }
}

// mol_vecs[m][:] = mean over 20 consecutive atom rows (offset by 1), fp32 out
__global__ __launch_bounds__(256) void mol_mean_k(
    const bf16_t* __restrict__ atom_h, float* __restrict__ out)
{
    int idx = blockIdx.x * blockDim.x + threadIdx.x;
    if (idx >= N_MOLS * 75) return;
    int m  = idx / 75;
    int c4 = idx - m * 75;
    const bf16_t* base = atom_h + (size_t)(1 + m * APM) * HIDDEN + c4 * 4;
    float4 s = make_float4(0.f, 0.f, 0.f, 0.f);
    #pragma unroll
    for (int i = 0; i < APM; ++i) {
        ushort4 u = *(const ushort4*)(base + (size_t)i * HIDDEN);
        s.x += bf2f(u.x); s.y += bf2f(u.y); s.z += bf2f(u.z); s.w += bf2f(u.w);
    }
    const float inv = 1.0f / (float)APM;
    s.x *= inv; s.y *= inv; s.z *= inv; s.w *= inv;
    *(float4*)(out + (size_t)m * HIDDEN + c4 * 4) = s;
}

// ---------------------------------------------------------------------------
extern "C" void kernel_launch(void* const* d_in, const int* in_sizes, int n_in,
                              void* d_out, int out_size, void* d_ws, size_t ws_size,
                              hipStream_t stream)
{
    const float* f_atoms = (const float*)d_in[0];
    const float* f_bonds = (const float*)d_in[1];
    const float* W_i     = (const float*)d_in[2];
    const float* W_h     = (const float*)d_in[3];
    const float* W_o     = (const float*)d_in[4];
    const float* b_o     = (const float*)d_in[5];
    const int*   a2b     = (const int*)d_in[6];
    const int*   b2a     = (const int*)d_in[7];
    const int*   b2revb  = (const int*)d_in[8];
    float* out = (float*)d_out;

    // Workspace: r2/r5/r6-proven layout (300,002,136 B — do NOT grow d_ws!)
    char* base = (char*)d_ws;
    const size_t SZ_BOND_B = (((size_t)MB_ROWS * HIDDEN * sizeof(bf16_t)) + 255) & ~(size_t)255;
    bf16_t* inp  = (bf16_t*)(base);
    bf16_t* msgA = (bf16_t*)(base + SZ_BOND_B);
    bf16_t* amsg = (bf16_t*)(base + 2 * SZ_BOND_B);

    // Pre-blocked bf16 weights live in d_out scratch (6 MB; 593,920 B used).
    // Safe: fully consumed before mol_mean_k overwrites every output element.
    char* scratch = (char*)d_out;
    bf16_t* Wib = (bf16_t*)(scratch);                 //  5 kb * 20480 B = 102,400
    bf16_t* Whb = (bf16_t*)(scratch + 102400);        // 10 kb           = 204,800
    bf16_t* Wob = (bf16_t*)(scratch + 307200);        // 14 kb           = 286,720

    dim3 blk512(512), blk256(256);
    const int gb = (MB_ROWS + 63) / 64;   // 3126
    const int ga = (MA_ROWS + 63) / 64;   // 1563
    const int agg_tasks  = ((MA_ROWS * 25) + 1) / 2;  // 1,250,013 (2 per thread)
    int agg_blocks  = (agg_tasks + 255) / 256;
    int mean_blocks = (N_MOLS * 75 + 255) / 256;

    // 0) weight prep (tiny)
    prep_w<<<(5  * CHUNKS_B + 255) / 256, blk256, 0, stream>>>(W_i, Wib, BOND_FDIM, 5 * CHUNKS_B, 0);
    prep_w<<<(10 * CHUNKS_B + 255) / 256, blk256, 0, stream>>>(W_h, Whb, HIDDEN, 10 * CHUNKS_B, 0);
    prep_w<<<(14 * CHUNKS_B + 255) / 256, blk256, 0, stream>>>(W_o, Wob, 436, 14 * CHUNKS_B, 1);

    // 1) inp = relu(f_bonds @ W_i)
    gemm_mfma<0, 5><<<gb, blk512, 0, stream>>>(
        f_bonds, nullptr, nullptr, nullptr, nullptr,
        Wib, nullptr, nullptr, inp, MB_ROWS);

    // 2) round 0: msgA = relu(inp + (agg -> gather-sub) @ W_h)
    aggregate_k<<<agg_blocks, blk256, 0, stream>>>(inp, a2b, amsg);
    gemm_mfma<1, 10><<<gb, blk512, 0, stream>>>(
        nullptr, amsg, inp, b2a, b2revb,
        Whb, nullptr, inp, msgA, MB_ROWS);

    // 3) round 1: inp = relu(inp + ...) in-place (same-element alias only)
    aggregate_k<<<agg_blocks, blk256, 0, stream>>>(msgA, a2b, amsg);
    gemm_mfma<1, 10><<<gb, blk512, 0, stream>>>(
        nullptr, amsg, msgA, b2a, b2revb,
        Whb, nullptr, inp, inp, MB_ROWS);

    // 4) readout: atom_h (=msgA) = relu([f_atoms | agg(inp)] @ W_o + b_o)
    aggregate_k<<<agg_blocks, blk256, 0, stream>>>(inp, a2b, amsg);
    gemm_mfma<2, 14><<<ga, blk512, 0, stream>>>(
        f_atoms, amsg, nullptr, nullptr, nullptr,
        Wob, b_o, nullptr, msgA, MA_ROWS);

    // 5) per-molecule mean
    mol_mean_k<<<mean_blocks, blk256, 0, stream>>>(msgA, out);
}

// Round 5
// 814.169 us; speedup vs baseline: 1.4817x; 1.0045x over previous
//
#include <hip/hip_runtime.h>
#include <hip/hip_bf16.h>

// Problem constants (fixed by reference setup_inputs)
#define N_ATOMS   100000
#define N_BONDS   200000
#define MAX_NB    6
#define HIDDEN    300
#define ATOM_FDIM 133
#define BOND_FDIM 147
#define N_MOLS    5000
#define APM       20      // atoms per mol

#define MB_ROWS (N_BONDS + 1)   // 200001
#define MA_ROWS (N_ATOMS + 1)   // 100001

#define CHUNKS_B 1280     // 16B chunks per k-block image: 4*320*8 bf16 = 20480 B
#define EPS      308      // epilogue LDS row stride in floats (300 cols + pad)
#define ROWP     65       // padded A-panel rows per qg (64 + 1)

typedef unsigned short bf16_t;
typedef __attribute__((ext_vector_type(8))) __bf16 bf16x8;   // MFMA A/B frag
typedef __attribute__((ext_vector_type(4))) float  float4v;  // MFMA C/D frag

__device__ __forceinline__ float bf2f(unsigned short u) {
    union { unsigned int i; float f; } x; x.i = ((unsigned int)u) << 16; return x.f;
}
__device__ __forceinline__ unsigned short f2bf(float f) {
    union { float f; unsigned int i; } x; x.f = f;
    unsigned int r = x.i + 0x7FFFu + ((x.i >> 16) & 1u);   // RNE (finite values)
    return (unsigned short)(r >> 16);
}

// ===========================================================================
// Weight prep: W fp32 -> bf16 k-block images. Chunk c of block kb holds, for
// q=c/320, col=c%320: Wv[kb*32+q*8+j][col], j=0..7 (zero-padded).
// perm=0: Wv[k] = W[k] for k<K.
// perm=1 (MODE2 image): virtual K layout [f_atoms 0..132 | pad 133..135 |
//         amsg 136..435] -> Wv[k] = W[k] (k<133), 0 (133..135), W[k-3]
//         (136..435), 0 beyond. Matches the MODE2 A-panel layout.
// ===========================================================================
__global__ __launch_bounds__(256) void prep_w(
    const float* __restrict__ W, bf16_t* __restrict__ dst, int K,
    int total_chunks, int perm)
{
    int idx = blockIdx.x * 256 + threadIdx.x;
    if (idx >= total_chunks) return;
    int kb  = idx / CHUNKS_B;
    int c   = idx - kb * CHUNKS_B;
    int cq  = c / 320;
    int col = c - cq * 320;
    unsigned short v[8];
    #pragma unroll
    for (int j = 0; j < 8; ++j) {
        int k = kb * 32 + cq * 8 + j;
        int ksrc;
        if (perm) ksrc = (k < 133) ? k : ((k >= 136 && k < 436) ? k - 3 : -1);
        else      ksrc = (k < K) ? k : -1;
        float f = (ksrc >= 0 && col < HIDDEN) ? W[(size_t)ksrc * HIDDEN + col] : 0.f;
        v[j] = f2bf(f);
    }
    bf16_t* p = dst + (size_t)idx * 8;
    *(ushort4*)(p)     = make_ushort4(v[0], v[1], v[2], v[3]);
    *(ushort4*)(p + 4) = make_ushort4(v[4], v[5], v[6], v[7]);
}

// ===========================================================================
// Full-A-panel MFMA GEMM, r5 revision:
//   - THE fix this round: all staging loads live in ONE branch-free basic
//     block terminated by __builtin_amdgcn_sched_barrier(0). r3 (branchy
//     ternaries) and r4 (pointer-selects, but no fence) both ended at
//     VGPR=48: the pre-RA scheduler sank every load to its use to cut
//     register pressure, re-serializing the gather. The fence forbids
//     crossing, so all ~20-34 loads issue back-to-back -> ONE latency
//     round. Verification signal: VGPR_Count must jump to ~90+.
//   - Tail tasks clamp the task index (duplicate same-value LDS write,
//     benign) instead of guarding -> no branches around loads.
//   - MODE 2 task space is region-major: tasks [0,1088) = fp32 region
//     (row=u/17, qg=u%17), tasks [0,2496) = bf16 region (row=u/39,
//     qg=17+u%39). Two separate branch-free load loops with different
//     shapes -> no per-task region branch splitting the scheduling region.
//   - As padded: (qg*65 + row)*8; k-loop: fully unrolled, B double-buffered
//     in registers straight from the pre-blocked global image; no barriers.
// Maps (verified r5/r6): A m=lane&15, k=q*8+j; B n=lane&15, k=q*8+j;
// C/D col=lane&15, row=q*4+reg.
// Block: 512 thr = 8 waves (2m x 4n); tile 64(m) x 320(n); wave 32m x 80n.
// MODE 0: A = f_bonds fp32 [M,147];            Y = relu(A@W)
// MODE 1: A = amsg[b2a[r]] - cur[b2revb[r]];   Y = relu(addend + A@W)
// MODE 2: A = [f_atoms(133)+pad3 | amsg(300)]; Y = relu(A@W + bias)
// ===========================================================================
template<int MODE, int KB>
__global__ __launch_bounds__(512, 4) void gemm_mfma(
    const float* __restrict__ Af,
    const bf16_t* __restrict__ Ab1, const bf16_t* __restrict__ Ab2,
    const int* __restrict__ b2a, const int* __restrict__ b2revb,
    const bf16_t* __restrict__ WB, const float* __restrict__ bias,
    const bf16_t* __restrict__ addend, bf16_t* __restrict__ Y,
    int M)
{
    const int S = HIDDEN;   // output row stride 300
    constexpr int QG    = KB * 4;                    // 8-col k-groups per row
    constexpr int TASKS = 64 * QG;
    constexpr int NT    = (TASKS + 511) / 512;       // staging tasks/thread
    // MODE 2 region split (KB=14: QG=56 = 17 fp32-region + 39 bf16-region)
    constexpr int T1  = 64 * 17;                     // 1088
    constexpr int T2  = 64 * 39;                     // 2496
    constexpr int NT1 = (T1 + 511) / 512;            // 3
    constexpr int NT2 = (T2 + 511) / 512;            // 5
    constexpr int ASZ   = QG * ROWP * 16;            // A-panel bytes (padded)
    constexpr int LDS_BYTES = (ASZ > 16 * EPS * 4) ? ASZ : 16 * EPS * 4;
    __shared__ __align__(16) char lds_pool[LDS_BYTES];
    bf16_t* As  = (bf16_t*)lds_pool;                 // [(qg*65+row)*8]
    float*  epi = (float*)lds_pool;                  // epilogue reuse
    __shared__ int rowmap[128];                      // MODE1: b2a | b2revb

    const int tid  = threadIdx.x;
    const int lane = tid & 63;
    const int w    = tid >> 6;        // 0..7
    const int wm   = w >> 2;          // m-half (0/1): 32 rows
    const int wn   = w & 3;           // n-quarter (0..3): 80 cols
    const int lrow = lane & 15;
    const int q    = lane >> 4;       // quad 0..3
    const int bm   = blockIdx.x * 64;

    // ---- MODE1: cache the per-row gather indices -------------------------
    if (MODE == 1) {
        if (tid < 64) {
            int sr = bm + tid;
            rowmap[tid] = (sr < M) ? b2a[sr] : 0;          // row 0 is all-zero
        } else if (tid < 128) {
            int sr = bm + tid - 64;
            rowmap[tid] = (sr < M) ? b2revb[sr] : 0;
        }
        __syncthreads();
    }

    const bf16_t* wptr = WB + (size_t)(q * 320 + wn * 80 + lrow) * 8;
    bf16x8 bcur[5], bnxt[5];

    // ---- staging phase 1: ONE branch-free load batch + scheduler fence ---
    ushort4 A0[MODE == 1 ? NT : 1], A1[MODE == 1 ? NT : 1];
    ushort4 C0[MODE == 1 ? NT : 1], C1[MODE == 1 ? NT : 1];
    float   F[MODE == 0 ? NT : 1][8];
    float   Ff[MODE == 2 ? NT1 : 1][8];
    ushort4 U0[MODE == 2 ? NT2 : 1], U1[MODE == 2 ? NT2 : 1];

    if (MODE == 1) {
        #pragma unroll
        for (int i = 0; i < NT; ++i) {
            int t = tid + i * 512;                   // TASKS%512==0 for KB=10
            int row = t / QG, qg = t - row * QG, k0 = qg * 8;
            const bf16_t* pa = Ab1 + (size_t)rowmap[row]      * S;
            const bf16_t* pc = Ab2 + (size_t)rowmap[64 + row] * S;
            // out-of-K-range -> Ab1 row 0 (all-zero): v_cndmask, no branch
            A0[i] = *(const ushort4*)((k0 + 4 <= S) ? pa + k0     : Ab1);
            A1[i] = *(const ushort4*)((k0 + 8 <= S) ? pa + k0 + 4 : Ab1);
            C0[i] = *(const ushort4*)((k0 + 4 <= S) ? pc + k0     : Ab1);
            C1[i] = *(const ushort4*)((k0 + 8 <= S) ? pc + k0 + 4 : Ab1);
        }
    } else if (MODE == 0) {
        #pragma unroll
        for (int i = 0; i < NT; ++i) {
            int t = tid + i * 512;
            t = (t < TASKS) ? t : TASKS - 1;         // tail: clamp, no branch
            int row = t / QG, qg = t - row * QG, k0 = qg * 8;
            int srow = bm + row;
            int rbase = srow * BOND_FDIM;
            #pragma unroll
            for (int j = 0; j < 8; ++j) {
                int k = k0 + j;
                // clamp to f_bonds[0][0] (=0): index select, no branch
                F[i][j] = Af[(srow < M && k < BOND_FDIM) ? rbase + k : 0];
            }
        }
    } else {   // MODE 2, region-major task space
        #pragma unroll
        for (int i = 0; i < NT1; ++i) {              // fp32 region
            int u = tid + i * 512;
            u = (u < T1) ? u : T1 - 1;
            int row = u / 17, qg = u - row * 17, k0 = qg * 8;
            int srow = bm + row;
            int rbase = srow * ATOM_FDIM;
            #pragma unroll
            for (int j = 0; j < 8; ++j) {
                int k = k0 + j;
                Ff[i][j] = Af[(srow < M && k < ATOM_FDIM) ? rbase + k : 0];
            }
        }
        #pragma unroll
        for (int i = 0; i < NT2; ++i) {              // bf16 region
            int u = tid + i * 512;
            u = (u < T2) ? u : T2 - 1;
            int row = u / 39, off = (u - row * 39) * 8;   // amsg col offset
            int srow = bm + row;
            const bf16_t* pm = Ab1 + (size_t)srow * S;
            bool ok = (srow < M);
            U0[i] = *(const ushort4*)((ok && off + 4 <= S) ? pm + off     : Ab1);
            U1[i] = *(const ushort4*)((ok && off + 8 <= S) ? pm + off + 4 : Ab1);
        }
    }
    // first B fragments join the same batch
    #pragma unroll
    for (int nt = 0; nt < 5; ++nt)
        bcur[nt] = *(const bf16x8*)(wptr + nt * 128);

    __builtin_amdgcn_sched_barrier(0);   // loads may NOT sink past this

    // ---- staging phase 2: convert + ds_write -----------------------------
    if (MODE == 1) {
        #pragma unroll
        for (int i = 0; i < NT; ++i) {
            int t = tid + i * 512;
            int row = t / QG, qg = t - row * QG;
            unsigned short av[8];
            av[0] = f2bf(bf2f(A0[i].x) - bf2f(C0[i].x));
            av[1] = f2bf(bf2f(A0[i].y) - bf2f(C0[i].y));
            av[2] = f2bf(bf2f(A0[i].z) - bf2f(C0[i].z));
            av[3] = f2bf(bf2f(A0[i].w) - bf2f(C0[i].w));
            av[4] = f2bf(bf2f(A1[i].x) - bf2f(C1[i].x));
            av[5] = f2bf(bf2f(A1[i].y) - bf2f(C1[i].y));
            av[6] = f2bf(bf2f(A1[i].z) - bf2f(C1[i].z));
            av[7] = f2bf(bf2f(A1[i].w) - bf2f(C1[i].w));
            bf16_t* dst = As + (size_t)(qg * ROWP + row) * 8;
            *(ushort4*)(dst)     = make_ushort4(av[0], av[1], av[2], av[3]);
            *(ushort4*)(dst + 4) = make_ushort4(av[4], av[5], av[6], av[7]);
        }
    } else if (MODE == 0) {
        #pragma unroll
        for (int i = 0; i < NT; ++i) {
            int t = tid + i * 512;
            t = (t < TASKS) ? t : TASKS - 1;
            int row = t / QG, qg = t - row * QG;
            unsigned short av[8];
            #pragma unroll
            for (int j = 0; j < 8; ++j) av[j] = f2bf(F[i][j]);
            bf16_t* dst = As + (size_t)(qg * ROWP + row) * 8;
            *(ushort4*)(dst)     = make_ushort4(av[0], av[1], av[2], av[3]);
            *(ushort4*)(dst + 4) = make_ushort4(av[4], av[5], av[6], av[7]);
        }
    } else {
        #pragma unroll
        for (int i = 0; i < NT1; ++i) {
            int u = tid + i * 512;
            u = (u < T1) ? u : T1 - 1;
            int row = u / 17, qg = u - row * 17;
            unsigned short av[8];
            #pragma unroll
            for (int j = 0; j < 8; ++j) av[j] = f2bf(Ff[i][j]);
            bf16_t* dst = As + (size_t)(qg * ROWP + row) * 8;
            *(ushort4*)(dst)     = make_ushort4(av[0], av[1], av[2], av[3]);
            *(ushort4*)(dst + 4) = make_ushort4(av[4], av[5], av[6], av[7]);
        }
        #pragma unroll
        for (int i = 0; i < NT2; ++i) {
            int u = tid + i * 512;
            u = (u < T2) ? u : T2 - 1;
            int row = u / 39, qg = 17 + (u - row * 39);
            bf16_t* dst = As + (size_t)(qg * ROWP + row) * 8;
            *(ushort4*)(dst)     = U0[i];            // raw bf16 passthrough
            *(ushort4*)(dst + 4) = U1[i];
        }
    }

    float4v acc[2][5];
    #pragma unroll
    for (int i = 0; i < 2; ++i)
        #pragma unroll
        for (int j = 0; j < 5; ++j) {
            float4v z = {0.f, 0.f, 0.f, 0.f};
            acc[i][j] = z;
        }

    __syncthreads();   // A-panel visible to all waves

    // ---- barrier-free k-loop: A from LDS, B double-buffered from global --
    #pragma unroll
    for (int kb = 0; kb < KB; ++kb) {
        const bf16_t* abase = As + (size_t)((kb * 4 + q) * ROWP + wm * 32 + lrow) * 8;
        bf16x8 af0 = *(const bf16x8*)(abase);
        bf16x8 af1 = *(const bf16x8*)(abase + 16 * 8);   // +16 rows
        if (kb + 1 < KB) {
            const bf16_t* wnx = wptr + (size_t)(kb + 1) * (CHUNKS_B * 8);
            #pragma unroll
            for (int nt = 0; nt < 5; ++nt)
                bnxt[nt] = *(const bf16x8*)(wnx + nt * 128);
        }
        #pragma unroll
        for (int nt = 0; nt < 5; ++nt) {
            if (wn * 80 + nt * 16 < HIDDEN) {   // skip all-pad tile (cols 304+)
                acc[0][nt] = __builtin_amdgcn_mfma_f32_16x16x32_bf16(af0, bcur[nt], acc[0][nt], 0, 0, 0);
                acc[1][nt] = __builtin_amdgcn_mfma_f32_16x16x32_bf16(af1, bcur[nt], acc[1][nt], 0, 0, 0);
            }
        }
        if (kb + 1 < KB) {
            #pragma unroll
            for (int nt = 0; nt < 5; ++nt) bcur[nt] = bnxt[nt];
        }
    }

    // ---- epilogue: LDS transpose -> coalesced ushort4 rows ---------------
    __syncthreads();   // safe to overwrite As pool
    #pragma unroll
    for (int mt = 0; mt < 2; ++mt) {
        for (int wh = 0; wh < 2; ++wh) {
            if (wm == wh) {
                #pragma unroll
                for (int nt = 0; nt < 5; ++nt) {
                    const int c0 = wn * 80 + nt * 16;
                    if (c0 < HIDDEN) {
                        #pragma unroll
                        for (int r = 0; r < 4; ++r)
                            epi[(q * 4 + r) * EPS + c0 + lrow] = acc[mt][nt][r];
                    }
                }
            }
            __syncthreads();
            const int row0 = bm + wh * 32 + mt * 16;
            for (int s = tid; s < 16 * 75; s += 512) {
                int rr = s / 75;
                int c4 = s - rr * 75;
                int grow = row0 + rr;
                if (grow < M) {
                    float4 v = *(const float4*)&epi[rr * EPS + c4 * 4];
                    if (MODE == 1) {
                        ushort4 ad = *(const ushort4*)(addend + (size_t)grow * S + c4 * 4);
                        v.x += bf2f(ad.x); v.y += bf2f(ad.y);
                        v.z += bf2f(ad.z); v.w += bf2f(ad.w);
                    }
                    if (MODE == 2) {
                        float4 bv = *(const float4*)(bias + c4 * 4);
                        v.x += bv.x; v.y += bv.y; v.z += bv.z; v.w += bv.w;
                    }
                    ushort4 o;
                    o.x = f2bf(v.x > 0.f ? v.x : 0.f);
                    o.y = f2bf(v.y > 0.f ? v.y : 0.f);
                    o.z = f2bf(v.z > 0.f ? v.z : 0.f);
                    o.w = f2bf(v.w > 0.f ? v.w : 0.f);
                    *(ushort4*)(Y + (size_t)grow * S + c4 * 4) = o;
                }
            }
            __syncthreads();   // before next stage overwrites epi
        }
    }
}

// ===========================================================================
// aggregate: amsg[a][:] = sum_j msg[a2b[a][j]][:]  (bf16, fp32 accumulate)
// r5: sched_barrier(0) fences so the 12 index loads and then the 36 row
// loads each issue as one batch (same load-sinking fix as the GEMM).
// ===========================================================================
__global__ __launch_bounds__(256, 4) void aggregate_k(
    const bf16_t* __restrict__ msg, const int* __restrict__ a2b,
    bf16_t* __restrict__ amsg)
{
    constexpr int TOT  = MA_ROWS * 25;       // 2,500,025 col-group tasks
    constexpr int HALF = (TOT + 1) / 2;      // 1,250,013
    int i0 = blockIdx.x * 256 + threadIdx.x;
    if (i0 >= HALF) return;
    int  i1   = i0 + HALF;
    bool has1 = (i1 < TOT);
    int  i1c  = has1 ? i1 : 0;               // clamp: atom 0 rows are zero
    int a0 = i0 / 25,  g0 = i0 - a0 * 25,  c0 = g0 * 12;
    int a1 = i1c / 25, g1 = i1c - a1 * 25, c1 = g1 * 12;

    const int* nb0 = a2b + (size_t)a0 * MAX_NB;
    const int* nb1 = a2b + (size_t)a1 * MAX_NB;
    int b0[MAX_NB], b1[MAX_NB];
    #pragma unroll
    for (int j = 0; j < MAX_NB; ++j) { b0[j] = nb0[j]; b1[j] = nb1[j]; }
    __builtin_amdgcn_sched_barrier(0);       // all 12 index loads first

    ushort4 u0[MAX_NB][3], u1[MAX_NB][3];
    #pragma unroll
    for (int j = 0; j < MAX_NB; ++j) {
        const bf16_t* p = msg + (size_t)b0[j] * HIDDEN + c0;
        u0[j][0] = *(const ushort4*)(p);
        u0[j][1] = *(const ushort4*)(p + 4);
        u0[j][2] = *(const ushort4*)(p + 8);
    }
    #pragma unroll
    for (int j = 0; j < MAX_NB; ++j) {
        const bf16_t* p = msg + (size_t)b1[j] * HIDDEN + c1;
        u1[j][0] = *(const ushort4*)(p);
        u1[j][1] = *(const ushort4*)(p + 4);
        u1[j][2] = *(const ushort4*)(p + 8);
    }
    __builtin_amdgcn_sched_barrier(0);       // all 36 row loads in flight

    float s0[12], s1[12];
    #pragma unroll
    for (int k = 0; k < 12; ++k) { s0[k] = 0.f; s1[k] = 0.f; }
    #pragma unroll
    for (int j = 0; j < MAX_NB; ++j) {
        #pragma unroll
        for (int h = 0; h < 3; ++h) {
            s0[h*4+0] += bf2f(u0[j][h].x); s0[h*4+1] += bf2f(u0[j][h].y);
            s0[h*4+2] += bf2f(u0[j][h].z); s0[h*4+3] += bf2f(u0[j][h].w);
            s1[h*4+0] += bf2f(u1[j][h].x); s1[h*4+1] += bf2f(u1[j][h].y);
            s1[h*4+2] += bf2f(u1[j][h].z); s1[h*4+3] += bf2f(u1[j][h].w);
        }
    }
    bf16_t* o0 = amsg + (size_t)a0 * HIDDEN + c0;
    *(ushort4*)(o0)     = make_ushort4(f2bf(s0[0]), f2bf(s0[1]), f2bf(s0[2]),  f2bf(s0[3]));
    *(ushort4*)(o0 + 4) = make_ushort4(f2bf(s0[4]), f2bf(s0[5]), f2bf(s0[6]),  f2bf(s0[7]));
    *(ushort4*)(o0 + 8) = make_ushort4(f2bf(s0[8]), f2bf(s0[9]), f2bf(s0[10]), f2bf(s0[11]));
    if (has1) {
        bf16_t* o1 = amsg + (size_t)a1 * HIDDEN + c1;
        *(ushort4*)(o1)     = make_ushort4(f2bf(s1[0]), f2bf(s1[1]), f2bf(s1[2]),  f2bf(s1[3]));
        *(ushort4*)(o1 + 4) = make_ushort4(f2bf(s1[4]), f2bf(s1[5]), f2bf(s1[6]),  f2bf(s1[7]));
        *(ushort4*)(o1 + 8) = make_ushort4(f2bf(s1[8]), f2bf(s1[9]), f2bf(s1[10]), f2bf(s1[11]));
    }
}

// mol_vecs[m][:] = mean over 20 consecutive atom rows (offset by 1), fp32 out
__global__ __launch_bounds__(256) void mol_mean_k(
    const bf16_t* __restrict__ atom_h, float* __restrict__ out)
{
    int idx = blockIdx.x * blockDim.x + threadIdx.x;
    if (idx >= N_MOLS * 75) return;
    int m  = idx / 75;
    int c4 = idx - m * 75;
    const bf16_t* base = atom_h + (size_t)(1 + m * APM) * HIDDEN + c4 * 4;
    float4 s = make_float4(0.f, 0.f, 0.f, 0.f);
    #pragma unroll
    for (int i = 0; i < APM; ++i) {
        ushort4 u = *(const ushort4*)(base + (size_t)i * HIDDEN);
        s.x += bf2f(u.x); s.y += bf2f(u.y); s.z += bf2f(u.z); s.w += bf2f(u.w);
    }
    const float inv = 1.0f / (float)APM;
    s.x *= inv; s.y *= inv; s.z *= inv; s.w *= inv;
    *(float4*)(out + (size_t)m * HIDDEN + c4 * 4) = s;
}

// ---------------------------------------------------------------------------
extern "C" void kernel_launch(void* const* d_in, const int* in_sizes, int n_in,
                              void* d_out, int out_size, void* d_ws, size_t ws_size,
                              hipStream_t stream)
{
    const float* f_atoms = (const float*)d_in[0];
    const float* f_bonds = (const float*)d_in[1];
    const float* W_i     = (const float*)d_in[2];
    const float* W_h     = (const float*)d_in[3];
    const float* W_o     = (const float*)d_in[4];
    const float* b_o     = (const float*)d_in[5];
    const int*   a2b     = (const int*)d_in[6];
    const int*   b2a     = (const int*)d_in[7];
    const int*   b2revb  = (const int*)d_in[8];
    float* out = (float*)d_out;

    // Workspace: r2/r5/r6-proven layout (300,002,136 B — do NOT grow d_ws!)
    char* base = (char*)d_ws;
    const size_t SZ_BOND_B = (((size_t)MB_ROWS * HIDDEN * sizeof(bf16_t)) + 255) & ~(size_t)255;
    bf16_t* inp  = (bf16_t*)(base);
    bf16_t* msgA = (bf16_t*)(base + SZ_BOND_B);
    bf16_t* amsg = (bf16_t*)(base + 2 * SZ_BOND_B);

    // Pre-blocked bf16 weights live in d_out scratch (6 MB; 593,920 B used).
    // Safe: fully consumed before mol_mean_k overwrites every output element.
    char* scratch = (char*)d_out;
    bf16_t* Wib = (bf16_t*)(scratch);                 //  5 kb * 20480 B = 102,400
    bf16_t* Whb = (bf16_t*)(scratch + 102400);        // 10 kb           = 204,800
    bf16_t* Wob = (bf16_t*)(scratch + 307200);        // 14 kb           = 286,720

    dim3 blk512(512), blk256(256);
    const int gb = (MB_ROWS + 63) / 64;   // 3126
    const int ga = (MA_ROWS + 63) / 64;   // 1563
    const int agg_tasks  = ((MA_ROWS * 25) + 1) / 2;  // 1,250,013 (2 per thread)
    int agg_blocks  = (agg_tasks + 255) / 256;
    int mean_blocks = (N_MOLS * 75 + 255) / 256;

    // 0) weight prep (tiny)
    prep_w<<<(5  * CHUNKS_B + 255) / 256, blk256, 0, stream>>>(W_i, Wib, BOND_FDIM, 5 * CHUNKS_B, 0);
    prep_w<<<(10 * CHUNKS_B + 255) / 256, blk256, 0, stream>>>(W_h, Whb, HIDDEN, 10 * CHUNKS_B, 0);
    prep_w<<<(14 * CHUNKS_B + 255) / 256, blk256, 0, stream>>>(W_o, Wob, 436, 14 * CHUNKS_B, 1);

    // 1) inp = relu(f_bonds @ W_i)
    gemm_mfma<0, 5><<<gb, blk512, 0, stream>>>(
        f_bonds, nullptr, nullptr, nullptr, nullptr,
        Wib, nullptr, nullptr, inp, MB_ROWS);

    // 2) round 0: msgA = relu(inp + (agg -> gather-sub) @ W_h)
    aggregate_k<<<agg_blocks, blk256, 0, stream>>>(inp, a2b, amsg);
    gemm_mfma<1, 10><<<gb, blk512, 0, stream>>>(
        nullptr, amsg, inp, b2a, b2revb,
        Whb, nullptr, inp, msgA, MB_ROWS);

    // 3) round 1: inp = relu(inp + ...) in-place (same-element alias only)
    aggregate_k<<<agg_blocks, blk256, 0, stream>>>(msgA, a2b, amsg);
    gemm_mfma<1, 10><<<gb, blk512, 0, stream>>>(
        nullptr, amsg, msgA, b2a, b2revb,
        Whb, nullptr, inp, inp, MB_ROWS);

    // 4) readout: atom_h (=msgA) = relu([f_atoms | agg(inp)] @ W_o + b_o)
    aggregate_k<<<agg_blocks, blk256, 0, stream>>>(inp, a2b, amsg);
    gemm_mfma<2, 14><<<ga, blk512, 0, stream>>>(
        f_atoms, amsg, nullptr, nullptr, nullptr,
        Wob, b_o, nullptr, msgA, MA_ROWS);

    // 5) per-molecule mean
    mol_mean_k<<<mean_blocks, blk256, 0, stream>>>(msgA, out);
}

// Round 6
// 811.676 us; speedup vs baseline: 1.4862x; 1.0031x over previous
//
#include <hip/hip_runtime.h>
#include <hip/hip_bf16.h>

// Problem constants (fixed by reference setup_inputs)
#define N_ATOMS   100000
#define N_BONDS   200000
#define MAX_NB    6
#define HIDDEN    300
#define ATOM_FDIM 133
#define BOND_FDIM 147
#define N_MOLS    5000
#define APM       20      // atoms per mol

#define MB_ROWS (N_BONDS + 1)   // 200001
#define MA_ROWS (N_ATOMS + 1)   // 100001

#define CHUNKS_B 1280     // 16B chunks per k-block image: 4*320*8 bf16 = 20480 B
#define EPS      308      // epilogue LDS row stride in floats (300 cols + pad)
#define ROWP     65       // padded A-panel rows per qg (64 + 1)

typedef unsigned short bf16_t;
typedef __attribute__((ext_vector_type(8))) __bf16 bf16x8;   // MFMA A/B frag
typedef __attribute__((ext_vector_type(4))) float  float4v;  // MFMA C/D frag
typedef __attribute__((ext_vector_type(2))) unsigned int uint2v;  // 8B load payload

__device__ __forceinline__ float bf2f(unsigned short u) {
    union { unsigned int i; float f; } x; x.i = ((unsigned int)u) << 16; return x.f;
}
__device__ __forceinline__ unsigned short f2bf(float f) {
    union { float f; unsigned int i; } x; x.f = f;
    unsigned int r = x.i + 0x7FFFu + ((x.i >> 16) & 1u);   // RNE (finite values)
    return (unsigned short)(r >> 16);
}
// bf16 pair packed in one u32: lo = bits<<16, hi = bits&0xffff0000
__device__ __forceinline__ float lo_f(unsigned int u) {
    union { unsigned int i; float f; } x; x.i = u << 16; return x.f;
}
__device__ __forceinline__ float hi_f(unsigned int u) {
    union { unsigned int i; float f; } x; x.i = u & 0xffff0000u; return x.f;
}

// Inline-asm 8B global load: the compiler can NOT sink/serialize these.
// r3/r4/r5 all failed to batch gathers via compiler loads (VGPR stuck at 48:
// pressure-driven sinking). Volatile asm pins issue order and forces the
// result live -> the whole batch stays in flight behind ONE vmcnt(0).
// NOTE counter discipline: compiler inserts NO waits for asm results (rule
// #18) -> manual s_waitcnt vmcnt(0) + sched_barrier(0) before first use;
// and all compiler-tracked vmem loads must be drained BEFORE the asm batch
// so later compiler-counted waits stay correct.
__device__ __forceinline__ void gload8(uint2v& d, const void* a) {
    asm volatile("global_load_dwordx2 %0, %1, off"
                 : "=v"(d) : "v"(a) : "memory");
}
#define VM_DRAIN() do {                                      \
    asm volatile("s_waitcnt vmcnt(0)" ::: "memory");         \
    __builtin_amdgcn_sched_barrier(0);                       \
} while (0)

// ===========================================================================
// Weight prep: W fp32 -> bf16 k-block images. Chunk c of block kb holds, for
// q=c/320, col=c%320: Wv[kb*32+q*8+j][col], j=0..7 (zero-padded).
// perm=0: Wv[k] = W[k] for k<K.
// perm=1 (MODE2 image): virtual K layout [f_atoms 0..132 | pad 133..135 |
//         amsg 136..435] -> Wv[k] = W[k] (k<133), 0 (133..135), W[k-3]
//         (136..435), 0 beyond. Matches the MODE2 A-panel layout.
// ===========================================================================
__global__ __launch_bounds__(256) void prep_w(
    const float* __restrict__ W, bf16_t* __restrict__ dst, int K,
    int total_chunks, int perm)
{
    int idx = blockIdx.x * 256 + threadIdx.x;
    if (idx >= total_chunks) return;
    int kb  = idx / CHUNKS_B;
    int c   = idx - kb * CHUNKS_B;
    int cq  = c / 320;
    int col = c - cq * 320;
    unsigned short v[8];
    #pragma unroll
    for (int j = 0; j < 8; ++j) {
        int k = kb * 32 + cq * 8 + j;
        int ksrc;
        if (perm) ksrc = (k < 133) ? k : ((k >= 136 && k < 436) ? k - 3 : -1);
        else      ksrc = (k < K) ? k : -1;
        float f = (ksrc >= 0 && col < HIDDEN) ? W[(size_t)ksrc * HIDDEN + col] : 0.f;
        v[j] = f2bf(f);
    }
    bf16_t* p = dst + (size_t)idx * 8;
    *(ushort4*)(p)     = make_ushort4(v[0], v[1], v[2], v[3]);
    *(ushort4*)(p + 4) = make_ushort4(v[4], v[5], v[6], v[7]);
}

// ===========================================================================
// Full-A-panel MFMA GEMM, r6 revision:
//   - MODE 1 staging gathers via INLINE-ASM global_load_dwordx2 (20 loads
//     back-to-back, one vmcnt(0) drain). Compiler-visible loads provably
//     never batch (r3/r4/r5: VGPR=48 across branchy / select / fenced
//     variants). Verification signal: VGPR_Count must jump to ~90+.
//   - Counter discipline: rowmap's __syncthreads drains compiler vmcnt to 0
//     before the asm batch; B fragments are loaded only AFTER the manual
//     drain, so compiler-counted waits remain valid.
//   - MODE 0/2 keep compiler loads (consecutive-row streaming, not gather).
//   - As padded: (qg*65 + row)*8; k-loop: fully unrolled, B double-buffered
//     in registers straight from the pre-blocked global image; no barriers.
// Maps (verified r5/r6): A m=lane&15, k=q*8+j; B n=lane&15, k=q*8+j;
// C/D col=lane&15, row=q*4+reg.
// Block: 512 thr = 8 waves (2m x 4n); tile 64(m) x 320(n); wave 32m x 80n.
// MODE 0: A = f_bonds fp32 [M,147];            Y = relu(A@W)
// MODE 1: A = amsg[b2a[r]] - cur[b2revb[r]];   Y = relu(addend + A@W)
// MODE 2: A = [f_atoms(133)+pad3 | amsg(300)]; Y = relu(A@W + bias)
// ===========================================================================
template<int MODE, int KB>
__global__ __launch_bounds__(512, 4) void gemm_mfma(
    const float* __restrict__ Af,
    const bf16_t* __restrict__ Ab1, const bf16_t* __restrict__ Ab2,
    const int* __restrict__ b2a, const int* __restrict__ b2revb,
    const bf16_t* __restrict__ WB, const float* __restrict__ bias,
    const bf16_t* __restrict__ addend, bf16_t* __restrict__ Y,
    int M)
{
    const int S = HIDDEN;   // output row stride 300
    constexpr int QG    = KB * 4;                    // 8-col k-groups per row
    constexpr int TASKS = 64 * QG;
    constexpr int NT    = (TASKS + 511) / 512;       // staging tasks/thread
    // MODE 2 region split (KB=14: QG=56 = 17 fp32-region + 39 bf16-region)
    constexpr int T1  = 64 * 17;                     // 1088
    constexpr int T2  = 64 * 39;                     // 2496
    constexpr int NT1 = (T1 + 511) / 512;            // 3
    constexpr int NT2 = (T2 + 511) / 512;            // 5
    constexpr int ASZ   = QG * ROWP * 16;            // A-panel bytes (padded)
    constexpr int LDS_BYTES = (ASZ > 16 * EPS * 4) ? ASZ : 16 * EPS * 4;
    __shared__ __align__(16) char lds_pool[LDS_BYTES];
    bf16_t* As  = (bf16_t*)lds_pool;                 // [(qg*65+row)*8]
    float*  epi = (float*)lds_pool;                  // epilogue reuse
    __shared__ int rowmap[128];                      // MODE1: b2a | b2revb

    const int tid  = threadIdx.x;
    const int lane = tid & 63;
    const int w    = tid >> 6;        // 0..7
    const int wm   = w >> 2;          // m-half (0/1): 32 rows
    const int wn   = w & 3;           // n-quarter (0..3): 80 cols
    const int lrow = lane & 15;
    const int q    = lane >> 4;       // quad 0..3
    const int bm   = blockIdx.x * 64;

    // ---- MODE1: cache the per-row gather indices -------------------------
    if (MODE == 1) {
        if (tid < 64) {
            int sr = bm + tid;
            rowmap[tid] = (sr < M) ? b2a[sr] : 0;          // row 0 is all-zero
        } else if (tid < 128) {
            int sr = bm + tid - 64;
            rowmap[tid] = (sr < M) ? b2revb[sr] : 0;
        }
        __syncthreads();   // also drains compiler vmcnt to 0 (b2a/b2revb)
    }

    const bf16_t* wptr = WB + (size_t)(q * 320 + wn * 80 + lrow) * 8;
    bf16x8 bcur[5], bnxt[5];

    // ---- staging phase 1: one load batch ---------------------------------
    uint2v A0[MODE == 1 ? NT : 1], A1[MODE == 1 ? NT : 1];
    uint2v C0g[MODE == 1 ? NT : 1], C1g[MODE == 1 ? NT : 1];
    float  F[MODE == 0 ? NT : 1][8];
    float  Ff[MODE == 2 ? NT1 : 1][8];
    ushort4 U0[MODE == 2 ? NT2 : 1], U1[MODE == 2 ? NT2 : 1];
    const ushort4 zz = make_ushort4(0, 0, 0, 0);

    if (MODE == 1) {
        // 20 asm gather loads, order-pinned, one drain
        #pragma unroll
        for (int i = 0; i < NT; ++i) {
            int t = tid + i * 512;                   // TASKS%512==0 for KB=10
            int row = t / QG, qg = t - row * QG, k0 = qg * 8;
            const bf16_t* pa = Ab1 + (size_t)rowmap[row]      * S;
            const bf16_t* pc = Ab2 + (size_t)rowmap[64 + row] * S;
            // out-of-K-range -> Ab1 row 0 (all-zero): v_cndmask, no branch
            gload8(A0[i],  (k0 + 4 <= S) ? (const void*)(pa + k0)     : (const void*)Ab1);
            gload8(A1[i],  (k0 + 8 <= S) ? (const void*)(pa + k0 + 4) : (const void*)Ab1);
            gload8(C0g[i], (k0 + 4 <= S) ? (const void*)(pc + k0)     : (const void*)Ab1);
            gload8(C1g[i], (k0 + 8 <= S) ? (const void*)(pc + k0 + 4) : (const void*)Ab1);
        }
        VM_DRAIN();
    } else if (MODE == 0) {
        #pragma unroll
        for (int i = 0; i < NT; ++i) {
            int t = tid + i * 512;
            t = (t < TASKS) ? t : TASKS - 1;         // tail: clamp, no branch
            int row = t / QG, qg = t - row * QG, k0 = qg * 8;
            int srow = bm + row;
            int rbase = srow * BOND_FDIM;
            #pragma unroll
            for (int j = 0; j < 8; ++j) {
                int k = k0 + j;
                // clamp to f_bonds[0][0] (=0): index select, no branch
                F[i][j] = Af[(srow < M && k < BOND_FDIM) ? rbase + k : 0];
            }
        }
    } else {   // MODE 2, region-major task space (streaming rows)
        #pragma unroll
        for (int i = 0; i < NT1; ++i) {              // fp32 region
            int u = tid + i * 512;
            u = (u < T1) ? u : T1 - 1;
            int row = u / 17, qg = u - row * 17, k0 = qg * 8;
            int srow = bm + row;
            int rbase = srow * ATOM_FDIM;
            #pragma unroll
            for (int j = 0; j < 8; ++j) {
                int k = k0 + j;
                Ff[i][j] = Af[(srow < M && k < ATOM_FDIM) ? rbase + k : 0];
            }
        }
        #pragma unroll
        for (int i = 0; i < NT2; ++i) {              // bf16 region
            int u = tid + i * 512;
            u = (u < T2) ? u : T2 - 1;
            int row = u / 39, off = (u - row * 39) * 8;   // amsg col offset
            int srow = bm + row;
            const bf16_t* pm = Ab1 + (size_t)srow * S;
            bool ok = (srow < M);
            U0[i] = *(const ushort4*)((ok && off + 4 <= S) ? pm + off     : Ab1);
            U1[i] = *(const ushort4*)((ok && off + 8 <= S) ? pm + off + 4 : Ab1);
        }
    }
    // first B fragments: for MODE1 AFTER the drain (counter discipline);
    // overlap converts + ds_write + syncthreads
    #pragma unroll
    for (int nt = 0; nt < 5; ++nt)
        bcur[nt] = *(const bf16x8*)(wptr + nt * 128);
    if (MODE != 1) __builtin_amdgcn_sched_barrier(0);

    // ---- staging phase 2: convert + ds_write -----------------------------
    if (MODE == 1) {
        #pragma unroll
        for (int i = 0; i < NT; ++i) {
            int t = tid + i * 512;
            int row = t / QG, qg = t - row * QG;
            unsigned short av[8];
            av[0] = f2bf(lo_f(A0[i].x) - lo_f(C0g[i].x));
            av[1] = f2bf(hi_f(A0[i].x) - hi_f(C0g[i].x));
            av[2] = f2bf(lo_f(A0[i].y) - lo_f(C0g[i].y));
            av[3] = f2bf(hi_f(A0[i].y) - hi_f(C0g[i].y));
            av[4] = f2bf(lo_f(A1[i].x) - lo_f(C1g[i].x));
            av[5] = f2bf(hi_f(A1[i].x) - hi_f(C1g[i].x));
            av[6] = f2bf(lo_f(A1[i].y) - lo_f(C1g[i].y));
            av[7] = f2bf(hi_f(A1[i].y) - hi_f(C1g[i].y));
            bf16_t* dst = As + (size_t)(qg * ROWP + row) * 8;
            *(ushort4*)(dst)     = make_ushort4(av[0], av[1], av[2], av[3]);
            *(ushort4*)(dst + 4) = make_ushort4(av[4], av[5], av[6], av[7]);
        }
    } else if (MODE == 0) {
        #pragma unroll
        for (int i = 0; i < NT; ++i) {
            int t = tid + i * 512;
            t = (t < TASKS) ? t : TASKS - 1;
            int row = t / QG, qg = t - row * QG;
            unsigned short av[8];
            #pragma unroll
            for (int j = 0; j < 8; ++j) av[j] = f2bf(F[i][j]);
            bf16_t* dst = As + (size_t)(qg * ROWP + row) * 8;
            *(ushort4*)(dst)     = make_ushort4(av[0], av[1], av[2], av[3]);
            *(ushort4*)(dst + 4) = make_ushort4(av[4], av[5], av[6], av[7]);
        }
    } else {
        #pragma unroll
        for (int i = 0; i < NT1; ++i) {
            int u = tid + i * 512;
            u = (u < T1) ? u : T1 - 1;
            int row = u / 17, qg = u - row * 17;
            unsigned short av[8];
            #pragma unroll
            for (int j = 0; j < 8; ++j) av[j] = f2bf(Ff[i][j]);
            bf16_t* dst = As + (size_t)(qg * ROWP + row) * 8;
            *(ushort4*)(dst)     = make_ushort4(av[0], av[1], av[2], av[3]);
            *(ushort4*)(dst + 4) = make_ushort4(av[4], av[5], av[6], av[7]);
        }
        #pragma unroll
        for (int i = 0; i < NT2; ++i) {
            int u = tid + i * 512;
            u = (u < T2) ? u : T2 - 1;
            int row = u / 39, qg = 17 + (u - row * 39);
            bf16_t* dst = As + (size_t)(qg * ROWP + row) * 8;
            *(ushort4*)(dst)     = U0[i];            // raw bf16 passthrough
            *(ushort4*)(dst + 4) = U1[i];
        }
    }

    float4v acc[2][5];
    #pragma unroll
    for (int i = 0; i < 2; ++i)
        #pragma unroll
        for (int j = 0; j < 5; ++j) {
            float4v z = {0.f, 0.f, 0.f, 0.f};
            acc[i][j] = z;
        }

    __syncthreads();   // A-panel visible to all waves

    // ---- barrier-free k-loop: A from LDS, B double-buffered from global --
    #pragma unroll
    for (int kb = 0; kb < KB; ++kb) {
        const bf16_t* abase = As + (size_t)((kb * 4 + q) * ROWP + wm * 32 + lrow) * 8;
        bf16x8 af0 = *(const bf16x8*)(abase);
        bf16x8 af1 = *(const bf16x8*)(abase + 16 * 8);   // +16 rows
        if (kb + 1 < KB) {
            const bf16_t* wnx = wptr + (size_t)(kb + 1) * (CHUNKS_B * 8);
            #pragma unroll
            for (int nt = 0; nt < 5; ++nt)
                bnxt[nt] = *(const bf16x8*)(wnx + nt * 128);
        }
        #pragma unroll
        for (int nt = 0; nt < 5; ++nt) {
            if (wn * 80 + nt * 16 < HIDDEN) {   // skip all-pad tile (cols 304+)
                acc[0][nt] = __builtin_amdgcn_mfma_f32_16x16x32_bf16(af0, bcur[nt], acc[0][nt], 0, 0, 0);
                acc[1][nt] = __builtin_amdgcn_mfma_f32_16x16x32_bf16(af1, bcur[nt], acc[1][nt], 0, 0, 0);
            }
        }
        if (kb + 1 < KB) {
            #pragma unroll
            for (int nt = 0; nt < 5; ++nt) bcur[nt] = bnxt[nt];
        }
    }

    // ---- epilogue: LDS transpose -> coalesced ushort4 rows ---------------
    __syncthreads();   // safe to overwrite As pool
    #pragma unroll
    for (int mt = 0; mt < 2; ++mt) {
        for (int wh = 0; wh < 2; ++wh) {
            if (wm == wh) {
                #pragma unroll
                for (int nt = 0; nt < 5; ++nt) {
                    const int c0 = wn * 80 + nt * 16;
                    if (c0 < HIDDEN) {
                        #pragma unroll
                        for (int r = 0; r < 4; ++r)
                            epi[(q * 4 + r) * EPS + c0 + lrow] = acc[mt][nt][r];
                    }
                }
            }
            __syncthreads();
            const int row0 = bm + wh * 32 + mt * 16;
            for (int s = tid; s < 16 * 75; s += 512) {
                int rr = s / 75;
                int c4 = s - rr * 75;
                int grow = row0 + rr;
                if (grow < M) {
                    float4 v = *(const float4*)&epi[rr * EPS + c4 * 4];
                    if (MODE == 1) {
                        ushort4 ad = *(const ushort4*)(addend + (size_t)grow * S + c4 * 4);
                        v.x += bf2f(ad.x); v.y += bf2f(ad.y);
                        v.z += bf2f(ad.z); v.w += bf2f(ad.w);
                    }
                    if (MODE == 2) {
                        float4 bv = *(const float4*)(bias + c4 * 4);
                        v.x += bv.x; v.y += bv.y; v.z += bv.z; v.w += bv.w;
                    }
                    ushort4 o;
                    o.x = f2bf(v.x > 0.f ? v.x : 0.f);
                    o.y = f2bf(v.y > 0.f ? v.y : 0.f);
                    o.z = f2bf(v.z > 0.f ? v.z : 0.f);
                    o.w = f2bf(v.w > 0.f ? v.w : 0.f);
                    *(ushort4*)(Y + (size_t)grow * S + c4 * 4) = o;
                }
            }
            __syncthreads();   // before next stage overwrites epi
        }
    }
}

// ===========================================================================
// aggregate: amsg[a][:] = sum_j msg[a2b[a][j]][:]  (bf16, fp32 accumulate)
// r6: the 36 row gathers are inline-asm loads (same fix as the GEMM).
// Counter discipline: an OR-chain over all 12 neighbor indices + empty asm
// forces the compiler to drain its own index loads (model=0=HW) before the
// asm batch; accumulate runs after one manual vmcnt(0) drain.
// ===========================================================================
__global__ __launch_bounds__(256, 4) void aggregate_k(
    const bf16_t* __restrict__ msg, const int* __restrict__ a2b,
    bf16_t* __restrict__ amsg)
{
    constexpr int TOT  = MA_ROWS * 25;       // 2,500,025 col-group tasks
    constexpr int HALF = (TOT + 1) / 2;      // 1,250,013
    int i0 = blockIdx.x * 256 + threadIdx.x;
    if (i0 >= HALF) return;
    int  i1   = i0 + HALF;
    bool has1 = (i1 < TOT);
    int  i1c  = has1 ? i1 : 0;               // clamp: atom 0 rows are zero
    int a0 = i0 / 25,  g0 = i0 - a0 * 25,  c0 = g0 * 12;
    int a1 = i1c / 25, g1 = i1c - a1 * 25, c1 = g1 * 12;

    const int* nb0 = a2b + (size_t)a0 * MAX_NB;
    const int* nb1 = a2b + (size_t)a1 * MAX_NB;
    int b0[MAX_NB], b1[MAX_NB];
    #pragma unroll
    for (int j = 0; j < MAX_NB; ++j) { b0[j] = nb0[j]; b1[j] = nb1[j]; }
    // force the compiler to wait out its own index loads HERE, so its vmcnt
    // model is 0 when the asm batch below starts inflating the HW counter
    int chk = 0;
    #pragma unroll
    for (int j = 0; j < MAX_NB; ++j) chk |= b0[j] | b1[j];
    asm volatile("" :: "v"(chk));
    __builtin_amdgcn_sched_barrier(0);

    uint2v R0[MAX_NB][3], R1[MAX_NB][3];
    #pragma unroll
    for (int j = 0; j < MAX_NB; ++j) {
        const bf16_t* p = msg + (size_t)b0[j] * HIDDEN + c0;
        gload8(R0[j][0], p);
        gload8(R0[j][1], p + 4);
        gload8(R0[j][2], p + 8);
    }
    #pragma unroll
    for (int j = 0; j < MAX_NB; ++j) {
        const bf16_t* p = msg + (size_t)b1[j] * HIDDEN + c1;
        gload8(R1[j][0], p);
        gload8(R1[j][1], p + 4);
        gload8(R1[j][2], p + 8);
    }
    VM_DRAIN();   // 36 loads in flight -> one latency round

    float s0[12], s1[12];
    #pragma unroll
    for (int k = 0; k < 12; ++k) { s0[k] = 0.f; s1[k] = 0.f; }
    #pragma unroll
    for (int j = 0; j < MAX_NB; ++j) {
        #pragma unroll
        for (int h = 0; h < 3; ++h) {
            s0[h*4+0] += lo_f(R0[j][h].x); s0[h*4+1] += hi_f(R0[j][h].x);
            s0[h*4+2] += lo_f(R0[j][h].y); s0[h*4+3] += hi_f(R0[j][h].y);
            s1[h*4+0] += lo_f(R1[j][h].x); s1[h*4+1] += hi_f(R1[j][h].x);
            s1[h*4+2] += lo_f(R1[j][h].y); s1[h*4+3] += hi_f(R1[j][h].y);
        }
    }
    bf16_t* o0 = amsg + (size_t)a0 * HIDDEN + c0;
    *(ushort4*)(o0)     = make_ushort4(f2bf(s0[0]), f2bf(s0[1]), f2bf(s0[2]),  f2bf(s0[3]));
    *(ushort4*)(o0 + 4) = make_ushort4(f2bf(s0[4]), f2bf(s0[5]), f2bf(s0[6]),  f2bf(s0[7]));
    *(ushort4*)(o0 + 8) = make_ushort4(f2bf(s0[8]), f2bf(s0[9]), f2bf(s0[10]), f2bf(s0[11]));
    if (has1) {
        bf16_t* o1 = amsg + (size_t)a1 * HIDDEN + c1;
        *(ushort4*)(o1)     = make_ushort4(f2bf(s1[0]), f2bf(s1[1]), f2bf(s1[2]),  f2bf(s1[3]));
        *(ushort4*)(o1 + 4) = make_ushort4(f2bf(s1[4]), f2bf(s1[5]), f2bf(s1[6]),  f2bf(s1[7]));
        *(ushort4*)(o1 + 8) = make_ushort4(f2bf(s1[8]), f2bf(s1[9]), f2bf(s1[10]), f2bf(s1[11]));
    }
}

// mol_vecs[m][:] = mean over 20 consecutive atom rows (offset by 1), fp32 out
__global__ __launch_bounds__(256) void mol_mean_k(
    const bf16_t* __restrict__ atom_h, float* __restrict__ out)
{
    int idx = blockIdx.x * blockDim.x + threadIdx.x;
    if (idx >= N_MOLS * 75) return;
    int m  = idx / 75;
    int c4 = idx - m * 75;
    const bf16_t* base = atom_h + (size_t)(1 + m * APM) * HIDDEN + c4 * 4;
    float4 s = make_float4(0.f, 0.f, 0.f, 0.f);
    #pragma unroll
    for (int i = 0; i < APM; ++i) {
        ushort4 u = *(const ushort4*)(base + (size_t)i * HIDDEN);
        s.x += bf2f(u.x); s.y += bf2f(u.y); s.z += bf2f(u.z); s.w += bf2f(u.w);
    }
    const float inv = 1.0f / (float)APM;
    s.x *= inv; s.y *= inv; s.z *= inv; s.w *= inv;
    *(float4*)(out + (size_t)m * HIDDEN + c4 * 4) = s;
}

// ---------------------------------------------------------------------------
extern "C" void kernel_launch(void* const* d_in, const int* in_sizes, int n_in,
                              void* d_out, int out_size, void* d_ws, size_t ws_size,
                              hipStream_t stream)
{
    const float* f_atoms = (const float*)d_in[0];
    const float* f_bonds = (const float*)d_in[1];
    const float* W_i     = (const float*)d_in[2];
    const float* W_h     = (const float*)d_in[3];
    const float* W_o     = (const float*)d_in[4];
    const float* b_o     = (const float*)d_in[5];
    const int*   a2b     = (const int*)d_in[6];
    const int*   b2a     = (const int*)d_in[7];
    const int*   b2revb  = (const int*)d_in[8];
    float* out = (float*)d_out;

    // Workspace: r2/r5/r6-proven layout (300,002,136 B — do NOT grow d_ws!)
    char* base = (char*)d_ws;
    const size_t SZ_BOND_B = (((size_t)MB_ROWS * HIDDEN * sizeof(bf16_t)) + 255) & ~(size_t)255;
    bf16_t* inp  = (bf16_t*)(base);
    bf16_t* msgA = (bf16_t*)(base + SZ_BOND_B);
    bf16_t* amsg = (bf16_t*)(base + 2 * SZ_BOND_B);

    // Pre-blocked bf16 weights live in d_out scratch (6 MB; 593,920 B used).
    // Safe: fully consumed before mol_mean_k overwrites every output element.
    char* scratch = (char*)d_out;
    bf16_t* Wib = (bf16_t*)(scratch);                 //  5 kb * 20480 B = 102,400
    bf16_t* Whb = (bf16_t*)(scratch + 102400);        // 10 kb           = 204,800
    bf16_t* Wob = (bf16_t*)(scratch + 307200);        // 14 kb           = 286,720

    dim3 blk512(512), blk256(256);
    const int gb = (MB_ROWS + 63) / 64;   // 3126
    const int ga = (MA_ROWS + 63) / 64;   // 1563
    const int agg_tasks  = ((MA_ROWS * 25) + 1) / 2;  // 1,250,013 (2 per thread)
    int agg_blocks  = (agg_tasks + 255) / 256;
    int mean_blocks = (N_MOLS * 75 + 255) / 256;

    // 0) weight prep (tiny)
    prep_w<<<(5  * CHUNKS_B + 255) / 256, blk256, 0, stream>>>(W_i, Wib, BOND_FDIM, 5 * CHUNKS_B, 0);
    prep_w<<<(10 * CHUNKS_B + 255) / 256, blk256, 0, stream>>>(W_h, Whb, HIDDEN, 10 * CHUNKS_B, 0);
    prep_w<<<(14 * CHUNKS_B + 255) / 256, blk256, 0, stream>>>(W_o, Wob, 436, 14 * CHUNKS_B, 1);

    // 1) inp = relu(f_bonds @ W_i)
    gemm_mfma<0, 5><<<gb, blk512, 0, stream>>>(
        f_bonds, nullptr, nullptr, nullptr, nullptr,
        Wib, nullptr, nullptr, inp, MB_ROWS);

    // 2) round 0: msgA = relu(inp + (agg -> gather-sub) @ W_h)
    aggregate_k<<<agg_blocks, blk256, 0, stream>>>(inp, a2b, amsg);
    gemm_mfma<1, 10><<<gb, blk512, 0, stream>>>(
        nullptr, amsg, inp, b2a, b2revb,
        Whb, nullptr, inp, msgA, MB_ROWS);

    // 3) round 1: inp = relu(inp + ...) in-place (same-element alias only)
    aggregate_k<<<agg_blocks, blk256, 0, stream>>>(msgA, a2b, amsg);
    gemm_mfma<1, 10><<<gb, blk512, 0, stream>>>(
        nullptr, amsg, msgA, b2a, b2revb,
        Whb, nullptr, inp, inp, MB_ROWS);

    // 4) readout: atom_h (=msgA) = relu([f_atoms | agg(inp)] @ W_o + b_o)
    aggregate_k<<<agg_blocks, blk256, 0, stream>>>(inp, a2b, amsg);
    gemm_mfma<2, 14><<<ga, blk512, 0, stream>>>(
        f_atoms, amsg, nullptr, nullptr, nullptr,
        Wob, b_o, nullptr, msgA, MA_ROWS);

    // 5) per-molecule mean
    mol_mean_k<<<mean_blocks, blk256, 0, stream>>>(msgA, out);
}